// Round 1
// baseline (1041.844 us; speedup 1.0000x reference)
//
#include <hip/hip_runtime.h>
#include <hip/hip_bf16.h>
#include <cstdint>

typedef __hip_bfloat16 bf16;
typedef __attribute__((ext_vector_type(8))) short short8;
typedef __attribute__((ext_vector_type(4))) float f32x4;

#define L_SEQ 2048
#define HID_  1024
#define NH    16
#define HD    64
#define FF_   4096
#define NPOS  257   // 2W+1
#define WHALF 128

__device__ inline float b2f_raw(unsigned short u) {
    union { unsigned int i; float f; } c; c.i = ((unsigned int)u) << 16; return c.f;
}
__device__ inline float b2f(bf16 v) { return __bfloat162float(v); }

// ---------------- weight conversion ----------------
// dst[n][k] = bf16(src[k][n]); src is [K][N] row-major, K is a power of two.
__global__ void k_transpose_convert(const float* __restrict__ src, bf16* __restrict__ dst,
                                    int K, int N, int kshift) {
    int total = K * N;
    for (int idx = blockIdx.x * blockDim.x + threadIdx.x; idx < total;
         idx += gridDim.x * blockDim.x) {
        int n = idx >> kshift;
        int k = idx & (K - 1);
        dst[idx] = __float2bfloat16(src[(size_t)k * N + n]);
    }
}

__global__ void k_copy_convert(const float* __restrict__ src, bf16* __restrict__ dst, int total) {
    for (int idx = blockIdx.x * blockDim.x + threadIdx.x; idx < total;
         idx += gridDim.x * blockDim.x) {
        dst[idx] = __float2bfloat16(src[idx]);
    }
}

// ---------------- layernorm ----------------
__global__ __launch_bounds__(256) void k_layernorm(const float* __restrict__ x,
                                                   const float* __restrict__ g,
                                                   const float* __restrict__ b,
                                                   bf16* __restrict__ out) {
    const int row = blockIdx.x, tid = threadIdx.x;
    const int lane = tid & 63, w = tid >> 6;
    const float4 v = *(const float4*)(x + (size_t)row * HID_ + tid * 4);
    float vals[4] = {v.x, v.y, v.z, v.w};
    float s = vals[0] + vals[1] + vals[2] + vals[3];
    float ss = vals[0]*vals[0] + vals[1]*vals[1] + vals[2]*vals[2] + vals[3]*vals[3];
    for (int off = 32; off; off >>= 1) { s += __shfl_down(s, off); ss += __shfl_down(ss, off); }
    __shared__ float rs[4], rss[4], mv[2];
    if (lane == 0) { rs[w] = s; rss[w] = ss; }
    __syncthreads();
    if (tid == 0) {
        float S = rs[0] + rs[1] + rs[2] + rs[3];
        float SS = rss[0] + rss[1] + rss[2] + rss[3];
        float mean = S * (1.0f / HID_);
        float var = SS * (1.0f / HID_) - mean * mean;
        mv[0] = mean; mv[1] = rsqrtf(var + 1e-8f);
    }
    __syncthreads();
    const float mean = mv[0], rstd = mv[1];
    #pragma unroll
    for (int e = 0; e < 4; ++e) {
        int c = tid * 4 + e;
        out[(size_t)row * HID_ + c] = __float2bfloat16((vals[e] - mean) * rstd * g[c] + b[c]);
    }
}

// ---------------- bf16 MFMA GEMM: C[M,N] = A[M,K] * B[N,K]^T ----------------
// EPI 0: outB = bf16(v)
// EPI 1: outF = v + bias[col] + res[row*N+col]   (fp32 out)
// EPI 2: outB = bf16(gelu_exact(v + bias[col]))
template <int EPI>
__global__ __launch_bounds__(256) void k_gemm(const bf16* __restrict__ A,
                                              const bf16* __restrict__ B,
                                              bf16* __restrict__ outB,
                                              float* __restrict__ outF,
                                              const float* __restrict__ bias,
                                              const float* __restrict__ res,
                                              int M, int N, int K) {
    __shared__ __align__(16) short As[128][40];
    __shared__ __align__(16) short Bs[128][40];
    const int tid = threadIdx.x;
    const int bm = blockIdx.x * 128, bn = blockIdx.y * 128;
    const int lane = tid & 63, w = tid >> 6;
    const int wm = (w >> 1) * 64, wn = (w & 1) * 64;
    f32x4 acc[4][4] = {};
    const short* Ag = (const short*)A;
    const short* Bg = (const short*)B;
    const int r0 = tid >> 2, kk0 = (tid & 3) << 3;
    const int r1 = r0 + 64;

    for (int k0 = 0; k0 < K; k0 += 32) {
        __syncthreads();
        *(short8*)&As[r0][kk0] = *(const short8*)&Ag[(size_t)(bm + r0) * K + k0 + kk0];
        *(short8*)&As[r1][kk0] = *(const short8*)&Ag[(size_t)(bm + r1) * K + k0 + kk0];
        *(short8*)&Bs[r0][kk0] = *(const short8*)&Bg[(size_t)(bn + r0) * K + k0 + kk0];
        *(short8*)&Bs[r1][kk0] = *(const short8*)&Bg[(size_t)(bn + r1) * K + k0 + kk0];
        __syncthreads();
        short8 af[4], bfr[4];
        const int fr = lane & 15, kg = (lane >> 4) << 3;
        #pragma unroll
        for (int f = 0; f < 4; ++f) {
            af[f]  = *(const short8*)&As[wm + f * 16 + fr][kg];
            bfr[f] = *(const short8*)&Bs[wn + f * 16 + fr][kg];
        }
        #pragma unroll
        for (int i = 0; i < 4; ++i)
            #pragma unroll
            for (int j = 0; j < 4; ++j)
                acc[i][j] = __builtin_amdgcn_mfma_f32_16x16x32_bf16(af[i], bfr[j], acc[i][j], 0, 0, 0);
    }

    const int cr = (lane >> 4) << 2, cc = lane & 15;
    #pragma unroll
    for (int i = 0; i < 4; ++i) {
        #pragma unroll
        for (int j = 0; j < 4; ++j) {
            const int col = bn + wn + j * 16 + cc;
            #pragma unroll
            for (int e = 0; e < 4; ++e) {
                const int row = bm + wm + i * 16 + cr + e;
                const size_t o = (size_t)row * N + col;
                float v = acc[i][j][e];
                if (EPI == 0) {
                    outB[o] = __float2bfloat16(v);
                } else if (EPI == 1) {
                    outF[o] = v + bias[col] + res[o];
                } else {
                    float xg = v + bias[col];
                    float gl = 0.5f * xg * (1.0f + erff(xg * 0.70710678f));
                    outB[o] = __float2bfloat16(gl);
                }
            }
        }
    }
}

// ---------------- relative-position projections ----------------
// out[h][i][t] = sum_d X[i][h*64+d] * P[h][d][t]
__global__ __launch_bounds__(320) void k_relpos(const bf16* __restrict__ X,
                                                const bf16* __restrict__ P,
                                                bf16* __restrict__ out) {
    const int i = blockIdx.x, h = blockIdx.y, tid = threadIdx.x;
    __shared__ float xs[HD];
    if (tid < HD) xs[tid] = b2f(X[(size_t)i * HID_ + h * HD + tid]);
    __syncthreads();
    if (tid < NPOS) {
        float acc = 0.f;
        const bf16* p = P + (size_t)(h * HD) * NPOS + tid;
        #pragma unroll 8
        for (int d = 0; d < HD; ++d) acc += xs[d] * b2f(p[(size_t)d * NPOS]);
        out[((size_t)h * L_SEQ + i) * NPOS + tid] = __float2bfloat16(acc);
    }
}

// ---------------- fused banded attention: scores + softmax + PV ----------------
__global__ __launch_bounds__(256) void k_attn(const bf16* __restrict__ qb,
                                              const bf16* __restrict__ kb,
                                              const bf16* __restrict__ vb,
                                              const bf16* __restrict__ c2p,
                                              const bf16* __restrict__ p2c,
                                              bf16* __restrict__ ctxb) {
    const int qi = blockIdx.x, h = blockIdx.y, tid = threadIdx.x;
    const int lane = tid & 63, w = tid >> 6;
    __shared__ float qs[HD];
    __shared__ float s[NPOS];
    __shared__ float sred[5];
    __shared__ float pv[4][HD];

    if (tid < HD) qs[tid] = b2f(qb[(size_t)qi * HID_ + h * HD + tid]);
    __syncthreads();

    float m = -3.4e38f;
    for (int t = tid; t < NPOS; t += 256) {
        const int j = qi - WHALF + t;
        float val = -3.4e38f;
        if (j >= 0 && j < L_SEQ) {
            const short8* kr = (const short8*)(kb + (size_t)j * HID_ + h * HD);
            float acc = 0.f;
            #pragma unroll
            for (int c8 = 0; c8 < 8; ++c8) {
                short8 kk = kr[c8];
                #pragma unroll
                for (int e = 0; e < 8; ++e)
                    acc += qs[c8 * 8 + e] * b2f_raw((unsigned short)kk[e]);
            }
            val = acc + b2f(c2p[((size_t)h * L_SEQ + qi) * NPOS + t])
                      + b2f(p2c[((size_t)h * L_SEQ + j) * NPOS + (2 * WHALF - t)]);
        }
        s[t] = val;
        m = fmaxf(m, val);
    }
    for (int off = 32; off; off >>= 1) m = fmaxf(m, __shfl_down(m, off));
    if (lane == 0) sred[w] = m;
    __syncthreads();
    if (tid == 0) sred[4] = fmaxf(fmaxf(sred[0], sred[1]), fmaxf(sred[2], sred[3]));
    __syncthreads();
    const float smax = sred[4];

    float loc = 0.f;
    for (int t = tid; t < NPOS; t += 256) {
        float p = __expf(s[t] - smax);
        s[t] = p;
        loc += p;
    }
    for (int off = 32; off; off >>= 1) loc += __shfl_down(loc, off);
    __syncthreads();
    if (lane == 0) sred[w] = loc;
    __syncthreads();
    if (tid == 0) sred[4] = sred[0] + sred[1] + sred[2] + sred[3];
    __syncthreads();
    const float rinv = 1.0f / sred[4];

    float acc = 0.f;
    for (int t = w; t < NPOS; t += 4) {
        const int j = qi - WHALF + t;
        if (j >= 0 && j < L_SEQ)
            acc += s[t] * b2f(vb[(size_t)j * HID_ + h * HD + lane]);
    }
    pv[w][lane] = acc;
    __syncthreads();
    if (tid < HD) {
        float c = (pv[0][tid] + pv[1][tid] + pv[2][tid] + pv[3][tid]) * rinv;
        ctxb[(size_t)qi * HID_ + h * HD + tid] = __float2bfloat16(c);
    }
}

// ---------------- launch ----------------
extern "C" void kernel_launch(void* const* d_in, const int* in_sizes, int n_in,
                              void* d_out, int out_size, void* d_ws, size_t ws_size,
                              hipStream_t stream) {
    const float* hid  = (const float*)d_in[0];
    const float* wq   = (const float*)d_in[2];
    const float* wk   = (const float*)d_in[3];
    const float* wv   = (const float*)d_in[4];
    const float* pk   = (const float*)d_in[5];
    const float* pq   = (const float*)d_in[6];
    const float* wo   = (const float*)d_in[7];
    const float* bo   = (const float*)d_in[8];
    const float* ln1g = (const float*)d_in[9];
    const float* ln1b = (const float*)d_in[10];
    const float* ln2g = (const float*)d_in[11];
    const float* ln2b = (const float*)d_in[12];
    const float* w1   = (const float*)d_in[13];
    const float* b1   = (const float*)d_in[14];
    const float* w2   = (const float*)d_in[15];
    const float* b2   = (const float*)d_in[16];
    float* out = (float*)d_out;

    char* ws = (char*)d_ws;
    size_t off = 0;
    auto alloc = [&](size_t bytes) -> void* {
        void* p = ws + off;
        off += (bytes + 255) & ~(size_t)255;
        return p;
    };
    bf16* wqb  = (bf16*)alloc((size_t)HID_ * HID_ * 2);
    bf16* wkb  = (bf16*)alloc((size_t)HID_ * HID_ * 2);
    bf16* wvb  = (bf16*)alloc((size_t)HID_ * HID_ * 2);
    bf16* wob  = (bf16*)alloc((size_t)HID_ * HID_ * 2);
    bf16* w1b  = (bf16*)alloc((size_t)HID_ * FF_ * 2);
    bf16* w2b  = (bf16*)alloc((size_t)HID_ * FF_ * 2);
    bf16* pkb  = (bf16*)alloc((size_t)NH * HD * NPOS * 2);
    bf16* pqb  = (bf16*)alloc((size_t)NH * HD * NPOS * 2);
    bf16* x1b  = (bf16*)alloc((size_t)L_SEQ * HID_ * 2);
    bf16* qbuf = (bf16*)alloc((size_t)L_SEQ * HID_ * 2);
    bf16* kbuf = (bf16*)alloc((size_t)L_SEQ * HID_ * 2);
    bf16* vbuf = (bf16*)alloc((size_t)L_SEQ * HID_ * 2);
    bf16* c2p  = (bf16*)alloc((size_t)NH * L_SEQ * NPOS * 2);
    bf16* p2c  = (bf16*)alloc((size_t)NH * L_SEQ * NPOS * 2);
    bf16* ctxb = (bf16*)alloc((size_t)L_SEQ * HID_ * 2);
    float* hbuf = (float*)alloc((size_t)L_SEQ * HID_ * 4);
    bf16* x2b  = (bf16*)alloc((size_t)L_SEQ * HID_ * 2);
    bf16* ffb  = (bf16*)alloc((size_t)L_SEQ * FF_ * 2);
    (void)ws_size; (void)in_sizes; (void)n_in; (void)out_size;

    // weight conversions (transposed to [N][K])
    k_transpose_convert<<<2048, 256, 0, stream>>>(wq, wqb, 1024, 1024, 10);
    k_transpose_convert<<<2048, 256, 0, stream>>>(wk, wkb, 1024, 1024, 10);
    k_transpose_convert<<<2048, 256, 0, stream>>>(wv, wvb, 1024, 1024, 10);
    k_transpose_convert<<<2048, 256, 0, stream>>>(wo, wob, 1024, 1024, 10);
    k_transpose_convert<<<2048, 256, 0, stream>>>(w1, w1b, 1024, 4096, 10); // dst [4096][1024]
    k_transpose_convert<<<2048, 256, 0, stream>>>(w2, w2b, 4096, 1024, 12); // dst [1024][4096]
    k_copy_convert<<<1028, 256, 0, stream>>>(pk, pkb, NH * HD * NPOS);
    k_copy_convert<<<1028, 256, 0, stream>>>(pq, pqb, NH * HD * NPOS);

    // LN1
    k_layernorm<<<L_SEQ, 256, 0, stream>>>(hid, ln1g, ln1b, x1b);

    // QKV projections
    dim3 g_small(L_SEQ / 128, HID_ / 128);   // 16 x 8
    dim3 g_ff1(L_SEQ / 128, FF_ / 128);      // 16 x 32
    k_gemm<0><<<g_small, 256, 0, stream>>>(x1b, wqb, qbuf, nullptr, nullptr, nullptr, L_SEQ, HID_, HID_);
    k_gemm<0><<<g_small, 256, 0, stream>>>(x1b, wkb, kbuf, nullptr, nullptr, nullptr, L_SEQ, HID_, HID_);
    k_gemm<0><<<g_small, 256, 0, stream>>>(x1b, wvb, vbuf, nullptr, nullptr, nullptr, L_SEQ, HID_, HID_);

    // relative position bias tables
    k_relpos<<<dim3(L_SEQ, NH), 320, 0, stream>>>(qbuf, pkb, c2p);
    k_relpos<<<dim3(L_SEQ, NH), 320, 0, stream>>>(kbuf, pqb, p2c);

    // banded attention
    k_attn<<<dim3(L_SEQ, NH), 256, 0, stream>>>(qbuf, kbuf, vbuf, c2p, p2c, ctxb);

    // Wo + bias + residual -> h (fp32)
    k_gemm<1><<<g_small, 256, 0, stream>>>(ctxb, wob, nullptr, hbuf, bo, hid, L_SEQ, HID_, HID_);

    // LN2
    k_layernorm<<<L_SEQ, 256, 0, stream>>>(hbuf, ln2g, ln2b, x2b);

    // FF1: gelu(x2 @ w1 + b1) -> bf16
    k_gemm<2><<<g_ff1, 256, 0, stream>>>(x2b, w1b, ffb, nullptr, b1, nullptr, L_SEQ, FF_, HID_);

    // FF2: h + (ff @ w2 + b2) -> out (fp32)
    k_gemm<1><<<g_small, 256, 0, stream>>>(ffb, w2b, nullptr, out, b2, hbuf, L_SEQ, HID_, FF_);
}

// Round 2
// 502.474 us; speedup vs baseline: 2.0734x; 2.0734x over previous
//
#include <hip/hip_runtime.h>
#include <hip/hip_bf16.h>
#include <cstdint>

typedef __hip_bfloat16 bf16;
typedef __attribute__((ext_vector_type(8))) short short8;
typedef __attribute__((ext_vector_type(4))) float f32x4;

#define L_SEQ 2048
#define HID_  1024
#define NH    16
#define HD    64
#define FF_   4096
#define NPOS  257   // 2W+1
#define WHALF 128

__device__ inline float b2f_raw(unsigned short u) {
    union { unsigned int i; float f; } c; c.i = ((unsigned int)u) << 16; return c.f;
}
__device__ inline float b2f(bf16 v) { return __bfloat162float(v); }
__device__ inline short f2bs(float f) {
    bf16 b = __float2bfloat16(f);
    return *reinterpret_cast<short*>(&b);
}

// ---------------- weight conversion ----------------
// dst[n][k] = bf16(src[k][n]); src is [K][N] row-major, K power of two.
__global__ void k_transpose_convert(const float* __restrict__ src, bf16* __restrict__ dst,
                                    int K, int N, int kshift) {
    int total = K * N;
    for (int idx = blockIdx.x * blockDim.x + threadIdx.x; idx < total;
         idx += gridDim.x * blockDim.x) {
        int n = idx >> kshift;
        int k = idx & (K - 1);
        dst[idx] = __float2bfloat16(src[(size_t)k * N + n]);
    }
}

// pos [H][64][257] fp32  ->  Pt [H][257][64] bf16
__global__ void k_pos_transpose(const float* __restrict__ src, bf16* __restrict__ dst) {
    const int total = NH * NPOS * HD;
    for (int idx = blockIdx.x * blockDim.x + threadIdx.x; idx < total;
         idx += gridDim.x * blockDim.x) {
        int d = idx & 63;
        int r = idx >> 6;
        int t = r % NPOS;
        int h = r / NPOS;
        dst[idx] = __float2bfloat16(src[((size_t)h * HD + d) * NPOS + t]);
    }
}

// ---------------- layernorm ----------------
__global__ __launch_bounds__(256) void k_layernorm(const float* __restrict__ x,
                                                   const float* __restrict__ g,
                                                   const float* __restrict__ b,
                                                   bf16* __restrict__ out) {
    const int row = blockIdx.x, tid = threadIdx.x;
    const int lane = tid & 63, w = tid >> 6;
    const float4 v = *(const float4*)(x + (size_t)row * HID_ + tid * 4);
    float vals[4] = {v.x, v.y, v.z, v.w};
    float s = vals[0] + vals[1] + vals[2] + vals[3];
    float ss = vals[0]*vals[0] + vals[1]*vals[1] + vals[2]*vals[2] + vals[3]*vals[3];
    for (int off = 32; off; off >>= 1) { s += __shfl_down(s, off); ss += __shfl_down(ss, off); }
    __shared__ float rs[4], rss[4], mv[2];
    if (lane == 0) { rs[w] = s; rss[w] = ss; }
    __syncthreads();
    if (tid == 0) {
        float S = rs[0] + rs[1] + rs[2] + rs[3];
        float SS = rss[0] + rss[1] + rss[2] + rss[3];
        float mean = S * (1.0f / HID_);
        float var = SS * (1.0f / HID_) - mean * mean;
        mv[0] = mean; mv[1] = rsqrtf(var + 1e-8f);
    }
    __syncthreads();
    const float mean = mv[0], rstd = mv[1];
    #pragma unroll
    for (int e = 0; e < 4; ++e) {
        int c = tid * 4 + e;
        out[(size_t)row * HID_ + c] = __float2bfloat16((vals[e] - mean) * rstd * g[c] + b[c]);
    }
}

// ---------------- bf16 MFMA GEMM: C[M,N] = A[M,K] * B[N,K]^T ----------------
template <int EPI>
__global__ __launch_bounds__(256) void k_gemm(const bf16* __restrict__ A,
                                              const bf16* __restrict__ B,
                                              bf16* __restrict__ outB,
                                              float* __restrict__ outF,
                                              const float* __restrict__ bias,
                                              const float* __restrict__ res,
                                              int M, int N, int K) {
    __shared__ __align__(16) short As[128][40];
    __shared__ __align__(16) short Bs[128][40];
    const int tid = threadIdx.x;
    const int bm = blockIdx.x * 128, bn = blockIdx.y * 128;
    const int lane = tid & 63, w = tid >> 6;
    const int wm = (w >> 1) * 64, wn = (w & 1) * 64;
    f32x4 acc[4][4] = {};
    const short* Ag = (const short*)A;
    const short* Bg = (const short*)B;
    const int r0 = tid >> 2, kk0 = (tid & 3) << 3;
    const int r1 = r0 + 64;

    for (int k0 = 0; k0 < K; k0 += 32) {
        __syncthreads();
        *(short8*)&As[r0][kk0] = *(const short8*)&Ag[(size_t)(bm + r0) * K + k0 + kk0];
        *(short8*)&As[r1][kk0] = *(const short8*)&Ag[(size_t)(bm + r1) * K + k0 + kk0];
        *(short8*)&Bs[r0][kk0] = *(const short8*)&Bg[(size_t)(bn + r0) * K + k0 + kk0];
        *(short8*)&Bs[r1][kk0] = *(const short8*)&Bg[(size_t)(bn + r1) * K + k0 + kk0];
        __syncthreads();
        short8 af[4], bfr[4];
        const int fr = lane & 15, kg = (lane >> 4) << 3;
        #pragma unroll
        for (int f = 0; f < 4; ++f) {
            af[f]  = *(const short8*)&As[wm + f * 16 + fr][kg];
            bfr[f] = *(const short8*)&Bs[wn + f * 16 + fr][kg];
        }
        #pragma unroll
        for (int i = 0; i < 4; ++i)
            #pragma unroll
            for (int j = 0; j < 4; ++j)
                acc[i][j] = __builtin_amdgcn_mfma_f32_16x16x32_bf16(af[i], bfr[j], acc[i][j], 0, 0, 0);
    }

    const int cr = (lane >> 4) << 2, cc = lane & 15;
    #pragma unroll
    for (int i = 0; i < 4; ++i) {
        #pragma unroll
        for (int j = 0; j < 4; ++j) {
            const int col = bn + wn + j * 16 + cc;
            #pragma unroll
            for (int e = 0; e < 4; ++e) {
                const int row = bm + wm + i * 16 + cr + e;
                const size_t o = (size_t)row * N + col;
                float v = acc[i][j][e];
                if (EPI == 0) {
                    outB[o] = __float2bfloat16(v);
                } else if (EPI == 1) {
                    outF[o] = v + bias[col] + res[o];
                } else {
                    float xg = v + bias[col];
                    float gl = 0.5f * xg * (1.0f + erff(xg * 0.70710678f));
                    outB[o] = __float2bfloat16(gl);
                }
            }
        }
    }
}

// ---------------- MFMA relpos: out[h][i][t] = X[i,h*64:]+... @ Pt[h][t][:] ----------------
// Per block: 64 rows (4 waves x 16) x 320 cols (t), K=64. No LDS.
__global__ __launch_bounds__(256) void k_relpos_mfma(const bf16* __restrict__ X,
                                                     const bf16* __restrict__ Pt,
                                                     bf16* __restrict__ out) {
    const int bq = blockIdx.x, h = blockIdx.y;
    const int qi0 = bq * 64;
    const int tid = threadIdx.x, lane = tid & 63, w = tid >> 6;
    const int fr = lane & 15, kg = (lane >> 4) << 3;
    const int cr = (lane >> 4) << 2, cc = lane & 15;

    short8 af[2];
    #pragma unroll
    for (int ks = 0; ks < 2; ++ks)
        af[ks] = *(const short8*)&X[(size_t)(qi0 + w * 16 + fr) * HID_ + h * HD + ks * 32 + kg];

    f32x4 acc[20];
    #pragma unroll
    for (int fj = 0; fj < 20; ++fj) acc[fj] = (f32x4){0.f, 0.f, 0.f, 0.f};

    #pragma unroll
    for (int fj = 0; fj < 20; ++fj) {
        int t = fj * 16 + fr;
        int tc = t < NPOS ? t : (NPOS - 1);
        #pragma unroll
        for (int ks = 0; ks < 2; ++ks) {
            short8 bp = *(const short8*)&Pt[((size_t)h * NPOS + tc) * HD + ks * 32 + kg];
            acc[fj] = __builtin_amdgcn_mfma_f32_16x16x32_bf16(af[ks], bp, acc[fj], 0, 0, 0);
        }
    }
    #pragma unroll
    for (int fj = 0; fj < 20; ++fj) {
        int t = fj * 16 + cc;
        if (t < NPOS) {
            #pragma unroll
            for (int e = 0; e < 4; ++e)
                out[((size_t)h * L_SEQ + qi0 + w * 16 + cr + e) * NPOS + t] =
                    __float2bfloat16(acc[fj][e]);
        }
    }
}

// ---------------- MFMA banded attention ----------------
// Block: head h x 64-query tile. Window: 320 keys [qi0-128, qi0+191].
// Wave w owns q-rows [w*16, w*16+16): softmax fully in-wave.
__global__ __launch_bounds__(256, 2) void k_attn_mfma(const bf16* __restrict__ qb,
                                                      const bf16* __restrict__ kb,
                                                      const bf16* __restrict__ vb,
                                                      const bf16* __restrict__ c2p,
                                                      const bf16* __restrict__ p2c,
                                                      bf16* __restrict__ ctxb) {
    const int bq = blockIdx.x, h = blockIdx.y;
    const int qi0 = bq * 64, j0 = qi0 - WHALF;
    const int tid = threadIdx.x, lane = tid & 63, w = tid >> 6;
    const int fr = lane & 15, kg = (lane >> 4) << 3;
    const int cr = (lane >> 4) << 2, cc = lane & 15;

    __shared__ short KVs[20480];      // K: [320][64] swizzled; then Vt: [64][320] swizzled
    __shared__ short Ps[64][168];     // P half-buffer: [64 q][160+8]
    char* KVb = (char*)KVs;

    // ---- load K window into LDS (XOR-swizzled rows) ----
    #pragma unroll
    for (int p = 0; p < 10; ++p) {
        int c = tid + p * 256;
        int t = c >> 3, d8 = (c & 7) << 3;
        int j = j0 + t;
        short8 v = {};
        if (j >= 0 && j < L_SEQ) v = *(const short8*)&kb[(size_t)j * HID_ + h * HD + d8];
        int byte = (t * 128 + d8 * 2) ^ ((t & 7) << 4);
        *(short8*)(KVb + byte) = v;
    }
    // Q fragments (A operand) straight from global
    short8 aq[2];
    #pragma unroll
    for (int ks = 0; ks < 2; ++ks)
        aq[ks] = *(const short8*)&qb[(size_t)(qi0 + w * 16 + fr) * HID_ + h * HD + ks * 32 + kg];
    __syncthreads();

    // ---- S = Q @ K^T : acc[fj][e] holds S[w*16+cr+e][fj*16+cc] ----
    f32x4 acc[20];
    #pragma unroll
    for (int fj = 0; fj < 20; ++fj) acc[fj] = (f32x4){0.f, 0.f, 0.f, 0.f};
    #pragma unroll
    for (int ks = 0; ks < 2; ++ks) {
        #pragma unroll
        for (int fj = 0; fj < 20; ++fj) {
            int t = fj * 16 + fr;
            int byte = (t * 128 + (ks * 32 + kg) * 2) ^ ((t & 7) << 4);
            short8 bk = *(const short8*)(KVb + byte);
            acc[fj] = __builtin_amdgcn_mfma_f32_16x16x32_bf16(aq[ks], bk, acc[fj], 0, 0, 0);
        }
    }
    __syncthreads();   // all waves done reading K region

    // ---- prefetch V into registers (latency hides under bias+softmax) ----
    short8 vreg[10];
    #pragma unroll
    for (int p = 0; p < 10; ++p) {
        int c = tid + p * 256;
        int t = c >> 3, d8 = (c & 7) << 3;
        int j = j0 + t;
        short8 v = {};
        if (j >= 0 && j < L_SEQ) v = *(const short8*)&vb[(size_t)j * HID_ + h * HD + d8];
        vreg[p] = v;
    }

    // ---- bias + band mask ----
    const int qrel0 = w * 16 + cr;
    #pragma unroll
    for (int fj = 0; fj < 20; ++fj) {
        int t = fj * 16 + cc;
        int j = j0 + t;
        #pragma unroll
        for (int e = 0; e < 4; ++e) {
            int qr = qrel0 + e;
            bool valid = (j >= 0) && (j < L_SEQ) && (t >= qr) && (t <= qr + 256);
            float sv = -3.0e38f;
            if (valid) {
                float b1v = b2f(c2p[((size_t)h * L_SEQ + qi0 + qr) * NPOS + (t - qr)]);
                float b2v = b2f(p2c[((size_t)h * L_SEQ + j) * NPOS + (256 - t + qr)]);
                sv = acc[fj][e] + b1v + b2v;
            }
            acc[fj][e] = sv;
        }
    }

    // ---- in-wave row softmax (reduce across the 16 cc lanes) ----
    float mx[4], sm[4];
    #pragma unroll
    for (int e = 0; e < 4; ++e) {
        float m = acc[0][e];
        #pragma unroll
        for (int fj = 1; fj < 20; ++fj) m = fmaxf(m, acc[fj][e]);
        mx[e] = m;
    }
    #pragma unroll
    for (int msk = 1; msk < 16; msk <<= 1)
        #pragma unroll
        for (int e = 0; e < 4; ++e) mx[e] = fmaxf(mx[e], __shfl_xor(mx[e], msk));
    #pragma unroll
    for (int e = 0; e < 4; ++e) sm[e] = 0.f;
    #pragma unroll
    for (int fj = 0; fj < 20; ++fj)
        #pragma unroll
        for (int e = 0; e < 4; ++e) {
            float p = __expf(acc[fj][e] - mx[e]);
            acc[fj][e] = p;
            sm[e] += p;
        }
    #pragma unroll
    for (int msk = 1; msk < 16; msk <<= 1)
        #pragma unroll
        for (int e = 0; e < 4; ++e) sm[e] += __shfl_xor(sm[e], msk);
    float rinv[4];
    #pragma unroll
    for (int e = 0; e < 4; ++e) rinv[e] = 1.0f / sm[e];

    // ---- write Vt (transposed, swizzled) into the K region ----
    #pragma unroll
    for (int p = 0; p < 10; ++p) {
        int c = tid + p * 256;
        int t = c >> 3, d8 = (c & 7) << 3;
        #pragma unroll
        for (int e = 0; e < 8; ++e) {
            int d = d8 + e;
            int byte = (d * 640 + t * 2) ^ ((d & 7) << 4);
            *(short*)(KVb + byte) = vreg[p][e];
        }
    }
    // ---- write P half 0 (cols 0..159), own rows only ----
    #pragma unroll
    for (int fj = 0; fj < 10; ++fj) {
        int col = fj * 16 + cc;
        #pragma unroll
        for (int e = 0; e < 4; ++e)
            Ps[w * 16 + cr + e][col] = f2bs(acc[fj][e]);
    }
    __syncthreads();   // Vt + P visible

    // ---- PV: ctx[q][d] += P[q,t] * V[t,d] ----
    f32x4 acc2[4];
    #pragma unroll
    for (int f = 0; f < 4; ++f) acc2[f] = (f32x4){0.f, 0.f, 0.f, 0.f};
    #pragma unroll
    for (int ks = 0; ks < 5; ++ks) {
        short8 pa = *(const short8*)&Ps[w * 16 + fr][ks * 32 + kg];
        #pragma unroll
        for (int f = 0; f < 4; ++f) {
            int d = f * 16 + fr;
            int tg = ks * 32 + kg;
            int byte = (d * 640 + tg * 2) ^ ((d & 7) << 4);
            short8 bv = *(const short8*)(KVb + byte);
            acc2[f] = __builtin_amdgcn_mfma_f32_16x16x32_bf16(pa, bv, acc2[f], 0, 0, 0);
        }
    }
    // ---- write P half 1 (cols 160..319); rows are wave-private, LDS in-order per wave ----
    #pragma unroll
    for (int fj = 10; fj < 20; ++fj) {
        int col = (fj - 10) * 16 + cc;
        #pragma unroll
        for (int e = 0; e < 4; ++e)
            Ps[w * 16 + cr + e][col] = f2bs(acc[fj][e]);
    }
    #pragma unroll
    for (int ks = 0; ks < 5; ++ks) {
        short8 pa = *(const short8*)&Ps[w * 16 + fr][ks * 32 + kg];
        #pragma unroll
        for (int f = 0; f < 4; ++f) {
            int d = f * 16 + fr;
            int tg = 160 + ks * 32 + kg;
            int byte = (d * 640 + tg * 2) ^ ((d & 7) << 4);
            short8 bv = *(const short8*)(KVb + byte);
            acc2[f] = __builtin_amdgcn_mfma_f32_16x16x32_bf16(pa, bv, acc2[f], 0, 0, 0);
        }
    }

    // ---- epilogue: normalize + store ----
    #pragma unroll
    for (int f = 0; f < 4; ++f)
        #pragma unroll
        for (int e = 0; e < 4; ++e) {
            int row = qi0 + w * 16 + cr + e;
            int d = f * 16 + cc;
            ctxb[(size_t)row * HID_ + h * HD + d] = __float2bfloat16(acc2[f][e] * rinv[e]);
        }
}

// ---------------- launch ----------------
extern "C" void kernel_launch(void* const* d_in, const int* in_sizes, int n_in,
                              void* d_out, int out_size, void* d_ws, size_t ws_size,
                              hipStream_t stream) {
    const float* hid  = (const float*)d_in[0];
    const float* wq   = (const float*)d_in[2];
    const float* wk   = (const float*)d_in[3];
    const float* wv   = (const float*)d_in[4];
    const float* pk   = (const float*)d_in[5];
    const float* pq   = (const float*)d_in[6];
    const float* wo   = (const float*)d_in[7];
    const float* bo   = (const float*)d_in[8];
    const float* ln1g = (const float*)d_in[9];
    const float* ln1b = (const float*)d_in[10];
    const float* ln2g = (const float*)d_in[11];
    const float* ln2b = (const float*)d_in[12];
    const float* w1   = (const float*)d_in[13];
    const float* b1   = (const float*)d_in[14];
    const float* w2   = (const float*)d_in[15];
    const float* b2   = (const float*)d_in[16];
    float* out = (float*)d_out;

    char* ws = (char*)d_ws;
    size_t off = 0;
    auto alloc = [&](size_t bytes) -> void* {
        void* p = ws + off;
        off += (bytes + 255) & ~(size_t)255;
        return p;
    };
    bf16* wqb  = (bf16*)alloc((size_t)HID_ * HID_ * 2);
    bf16* wkb  = (bf16*)alloc((size_t)HID_ * HID_ * 2);
    bf16* wvb  = (bf16*)alloc((size_t)HID_ * HID_ * 2);
    bf16* wob  = (bf16*)alloc((size_t)HID_ * HID_ * 2);
    bf16* w1b  = (bf16*)alloc((size_t)HID_ * FF_ * 2);
    bf16* w2b  = (bf16*)alloc((size_t)HID_ * FF_ * 2);
    bf16* pkt  = (bf16*)alloc((size_t)NH * NPOS * HD * 2);
    bf16* pqt  = (bf16*)alloc((size_t)NH * NPOS * HD * 2);
    bf16* x1b  = (bf16*)alloc((size_t)L_SEQ * HID_ * 2);
    bf16* qbuf = (bf16*)alloc((size_t)L_SEQ * HID_ * 2);
    bf16* kbuf = (bf16*)alloc((size_t)L_SEQ * HID_ * 2);
    bf16* vbuf = (bf16*)alloc((size_t)L_SEQ * HID_ * 2);
    bf16* c2p  = (bf16*)alloc((size_t)NH * L_SEQ * NPOS * 2);
    bf16* p2c  = (bf16*)alloc((size_t)NH * L_SEQ * NPOS * 2);
    bf16* ctxb = (bf16*)alloc((size_t)L_SEQ * HID_ * 2);
    float* hbuf = (float*)alloc((size_t)L_SEQ * HID_ * 4);
    bf16* x2b  = (bf16*)alloc((size_t)L_SEQ * HID_ * 2);
    bf16* ffb  = (bf16*)alloc((size_t)L_SEQ * FF_ * 2);
    (void)ws_size; (void)in_sizes; (void)n_in; (void)out_size;

    // weight conversions (transposed to [N][K])
    k_transpose_convert<<<2048, 256, 0, stream>>>(wq, wqb, 1024, 1024, 10);
    k_transpose_convert<<<2048, 256, 0, stream>>>(wk, wkb, 1024, 1024, 10);
    k_transpose_convert<<<2048, 256, 0, stream>>>(wv, wvb, 1024, 1024, 10);
    k_transpose_convert<<<2048, 256, 0, stream>>>(wo, wob, 1024, 1024, 10);
    k_transpose_convert<<<2048, 256, 0, stream>>>(w1, w1b, 1024, 4096, 10);
    k_transpose_convert<<<2048, 256, 0, stream>>>(w2, w2b, 4096, 1024, 12);
    k_pos_transpose<<<1028, 256, 0, stream>>>(pk, pkt);
    k_pos_transpose<<<1028, 256, 0, stream>>>(pq, pqt);

    // LN1
    k_layernorm<<<L_SEQ, 256, 0, stream>>>(hid, ln1g, ln1b, x1b);

    // QKV projections
    dim3 g_small(L_SEQ / 128, HID_ / 128);
    dim3 g_ff1(L_SEQ / 128, FF_ / 128);
    k_gemm<0><<<g_small, 256, 0, stream>>>(x1b, wqb, qbuf, nullptr, nullptr, nullptr, L_SEQ, HID_, HID_);
    k_gemm<0><<<g_small, 256, 0, stream>>>(x1b, wkb, kbuf, nullptr, nullptr, nullptr, L_SEQ, HID_, HID_);
    k_gemm<0><<<g_small, 256, 0, stream>>>(x1b, wvb, vbuf, nullptr, nullptr, nullptr, L_SEQ, HID_, HID_);

    // relative position tables via MFMA
    dim3 g_rp(L_SEQ / 64, NH);
    k_relpos_mfma<<<g_rp, 256, 0, stream>>>(qbuf, pkt, c2p);
    k_relpos_mfma<<<g_rp, 256, 0, stream>>>(kbuf, pqt, p2c);

    // banded attention (MFMA)
    k_attn_mfma<<<dim3(L_SEQ / 64, NH), 256, 0, stream>>>(qbuf, kbuf, vbuf, c2p, p2c, ctxb);

    // Wo + bias + residual -> h (fp32)
    k_gemm<1><<<g_small, 256, 0, stream>>>(ctxb, wob, nullptr, hbuf, bo, hid, L_SEQ, HID_, HID_);

    // LN2
    k_layernorm<<<L_SEQ, 256, 0, stream>>>(hbuf, ln2g, ln2b, x2b);

    // FF1: gelu(x2 @ w1 + b1) -> bf16
    k_gemm<2><<<g_ff1, 256, 0, stream>>>(x2b, w1b, ffb, nullptr, b1, nullptr, L_SEQ, FF_, HID_);

    // FF2: h + (ff @ w2 + b2) -> out (fp32)
    k_gemm<1><<<g_small, 256, 0, stream>>>(ffb, w2b, nullptr, out, b2, hbuf, L_SEQ, HID_, FF_);
}

// Round 5
// 340.925 us; speedup vs baseline: 3.0559x; 1.4739x over previous
//
#include <hip/hip_runtime.h>
#include <hip/hip_bf16.h>
#include <cstdint>

typedef __hip_bfloat16 bf16;
typedef __attribute__((ext_vector_type(8))) short short8;
typedef __attribute__((ext_vector_type(4))) float f32x4;
typedef __attribute__((address_space(1))) const unsigned int gu32;
typedef __attribute__((address_space(3))) unsigned int lu32;

#define L_SEQ 2048
#define HID_  1024
#define NH    16
#define HD    64
#define FF_   4096
#define NPOS  257   // 2W+1
#define WHALF 128
#define QKVS  3072  // fused qkv row stride

__device__ inline float b2f_raw(unsigned short u) {
    union { unsigned int i; float f; } c; c.i = ((unsigned int)u) << 16; return c.f;
}
__device__ inline float b2f(bf16 v) { return __bfloat162float(v); }
__device__ inline short f2bs(float f) {
    bf16 b = __float2bfloat16(f);
    return *reinterpret_cast<short*>(&b);
}

// ---------------- tiled transpose-convert: src fp32 [K][N] -> dst bf16 [N][K] ----------------
__global__ __launch_bounds__(256) void k_transpose_tiled(const float* __restrict__ src,
                                                         bf16* __restrict__ dst,
                                                         int K, int N) {
    const int k0 = blockIdx.x * 64, n0 = blockIdx.y * 64;
    __shared__ float t[64][65];
    const int c = threadIdx.x & 63, r4 = threadIdx.x >> 6;
    #pragma unroll
    for (int i = 0; i < 16; ++i)
        t[i * 4 + r4][c] = src[(size_t)(k0 + i * 4 + r4) * N + n0 + c];
    __syncthreads();
    #pragma unroll
    for (int i = 0; i < 16; ++i) {
        int n = i * 4 + r4;
        dst[(size_t)(n0 + n) * K + k0 + c] = __float2bfloat16(t[c][n]);
    }
}

// pos [H][64][257] fp32 -> Pt [H][257][64] bf16
__global__ void k_pos_transpose(const float* __restrict__ src, bf16* __restrict__ dst) {
    const int total = NH * NPOS * HD;
    for (int idx = blockIdx.x * blockDim.x + threadIdx.x; idx < total;
         idx += gridDim.x * blockDim.x) {
        int d = idx & 63;
        int r = idx >> 6;
        int t = r % NPOS;
        int h = r / NPOS;
        dst[idx] = __float2bfloat16(src[((size_t)h * HD + d) * NPOS + t]);
    }
}

// ---------------- layernorm ----------------
__global__ __launch_bounds__(256) void k_layernorm(const float* __restrict__ x,
                                                   const float* __restrict__ g,
                                                   const float* __restrict__ b,
                                                   bf16* __restrict__ out) {
    const int row = blockIdx.x, tid = threadIdx.x;
    const int lane = tid & 63, w = tid >> 6;
    const float4 v = *(const float4*)(x + (size_t)row * HID_ + tid * 4);
    float vals[4] = {v.x, v.y, v.z, v.w};
    float s = vals[0] + vals[1] + vals[2] + vals[3];
    float ss = vals[0]*vals[0] + vals[1]*vals[1] + vals[2]*vals[2] + vals[3]*vals[3];
    for (int off = 32; off; off >>= 1) { s += __shfl_down(s, off); ss += __shfl_down(ss, off); }
    __shared__ float rs[4], rss[4], mv[2];
    if (lane == 0) { rs[w] = s; rss[w] = ss; }
    __syncthreads();
    if (tid == 0) {
        float S = rs[0] + rs[1] + rs[2] + rs[3];
        float SS = rss[0] + rss[1] + rss[2] + rss[3];
        float mean = S * (1.0f / HID_);
        float var = SS * (1.0f / HID_) - mean * mean;
        mv[0] = mean; mv[1] = rsqrtf(var + 1e-8f);
    }
    __syncthreads();
    const float mean = mv[0], rstd = mv[1];
    #pragma unroll
    for (int e = 0; e < 4; ++e) {
        int c = tid * 4 + e;
        out[(size_t)row * HID_ + c] = __float2bfloat16((vals[e] - mean) * rstd * g[c] + b[c]);
    }
}

// ---------------- bf16 MFMA GEMM, 64x128 tile, global_load_lds + 2-phase dbuf ----------------
// C[M,N] = A[M,K] * B[N,K]^T, K-range [z*kTiles*32, (z+1)*kTiles*32)
// EPI 0: outB = bf16(v)                 (row stride N)
// EPI 2: outB = bf16(gelu(v+bias[col]))
// EPI 3: outF[z*MN + row*N + col] = v   (split-K partial)
template <int EPI>
__global__ __launch_bounds__(256) void k_gemm64(const bf16* __restrict__ A,
                                                const bf16* __restrict__ B,
                                                bf16* __restrict__ outB,
                                                float* __restrict__ outF,
                                                const float* __restrict__ bias,
                                                int N, int K, int kTiles, int MN) {
    __shared__ __align__(16) short As[2][2048];   // [64][32] swizzled
    __shared__ __align__(16) short Bs[2][4096];   // [128][32] swizzled
    const int tid = threadIdx.x;
    const int bm = blockIdx.x * 64, bn = blockIdx.y * 128;
    const int lane = tid & 63, w = tid >> 6;
    const int wr = w >> 1, wc = w & 1;            // wave tile: 32 x 64
    const int k0base = blockIdx.z * kTiles * 32;

    // staging geometry (pre-swizzled global source, linear LDS dest)
    const int crow = lane >> 2;                   // 0..15
    const int c16p = lane & 3;
    const int coll = (c16p ^ (crow & 3)) * 8;     // logical k element offset
    const short* Ag = (const short*)A;
    const short* Bg = (const short*)B;
    const size_t a_off = (size_t)(bm + w * 16 + crow) * K + coll;
    const size_t b_off0 = (size_t)(bn + w * 32 + crow) * K + coll;
    const size_t b_off1 = (size_t)(bn + w * 32 + 16 + crow) * K + coll;

    auto stage = [&](int buf, int k0) {
        __builtin_amdgcn_global_load_lds((gu32*)(Ag + a_off + k0), (lu32*)&As[buf][w * 512], 16, 0, 0);
        __builtin_amdgcn_global_load_lds((gu32*)(Bg + b_off0 + k0), (lu32*)&Bs[buf][w * 1024], 16, 0, 0);
        __builtin_amdgcn_global_load_lds((gu32*)(Bg + b_off1 + k0), (lu32*)&Bs[buf][w * 1024 + 512], 16, 0, 0);
    };

    // fragment read geometry (swizzled)
    const int fr = lane & 15, kq = lane >> 4;
    const int xbyte = ((kq ^ (fr & 3)) << 4);

    f32x4 acc[2][4] = {};
    stage(0, k0base);
    __syncthreads();

    for (int t = 0; t < kTiles; ++t) {
        if (t + 1 < kTiles) stage((t + 1) & 1, k0base + (t + 1) * 32);
        const char* Ab = (const char*)As[t & 1];
        const char* Bb = (const char*)Bs[t & 1];
        short8 af[2], bfv[4];
        #pragma unroll
        for (int m2 = 0; m2 < 2; ++m2)
            af[m2] = *(const short8*)(Ab + ((wr * 32 + m2 * 16 + fr) << 6) + xbyte);
        #pragma unroll
        for (int n2 = 0; n2 < 4; ++n2)
            bfv[n2] = *(const short8*)(Bb + ((wc * 64 + n2 * 16 + fr) << 6) + xbyte);
        #pragma unroll
        for (int m2 = 0; m2 < 2; ++m2)
            #pragma unroll
            for (int n2 = 0; n2 < 4; ++n2)
                acc[m2][n2] = __builtin_amdgcn_mfma_f32_16x16x32_bf16(af[m2], bfv[n2], acc[m2][n2], 0, 0, 0);
        __syncthreads();
    }

    const int cr = kq * 4, cc = fr;
    #pragma unroll
    for (int m2 = 0; m2 < 2; ++m2) {
        #pragma unroll
        for (int n2 = 0; n2 < 4; ++n2) {
            const int col = bn + wc * 64 + n2 * 16 + cc;
            #pragma unroll
            for (int e = 0; e < 4; ++e) {
                const int row = bm + wr * 32 + m2 * 16 + cr + e;
                const size_t o = (size_t)row * N + col;
                float v = acc[m2][n2][e];
                if (EPI == 0) {
                    outB[o] = __float2bfloat16(v);
                } else if (EPI == 2) {
                    float xg = v + bias[col];
                    float gl = 0.5f * xg * (1.0f + erff(xg * 0.70710678f));
                    outB[o] = __float2bfloat16(gl);
                } else {
                    outF[(size_t)blockIdx.z * MN + o] = v;
                }
            }
        }
    }
}

// ---------------- split-K reduce + bias + residual (N=1024, M=2048) ----------------
template <int S>
__global__ __launch_bounds__(256) void k_reduce(const float* __restrict__ parts,
                                                const float* __restrict__ bias,
                                                const float* __restrict__ res,
                                                float* __restrict__ out) {
    const int idx = blockIdx.x * 256 + threadIdx.x;  // float4 index over 2048*1024/4
    const float4* p = (const float4*)parts;
    float4 s = p[idx];
    #pragma unroll
    for (int ss = 1; ss < S; ++ss) {
        float4 t2 = p[idx + (size_t)ss * 524288];
        s.x += t2.x; s.y += t2.y; s.z += t2.z; s.w += t2.w;
    }
    float4 bb = ((const float4*)bias)[idx & 255];
    float4 rr = ((const float4*)res)[idx];
    float4 o = {s.x + bb.x + rr.x, s.y + bb.y + rr.y, s.z + bb.z + rr.z, s.w + bb.w + rr.w};
    ((float4*)out)[idx] = o;
}

// ---------------- MFMA relpos: out[h][i][t] = X[i,:] @ Pt[h][t][:] ----------------
__global__ __launch_bounds__(256) void k_relpos_mfma(const bf16* __restrict__ X,
                                                     const bf16* __restrict__ Pt,
                                                     bf16* __restrict__ out) {
    const int bq = blockIdx.x, h = blockIdx.y;
    const int qi0 = bq * 64;
    const int tid = threadIdx.x, lane = tid & 63, w = tid >> 6;
    const int fr = lane & 15, kg = (lane >> 4) << 3;
    const int cr = (lane >> 4) << 2, cc = lane & 15;

    short8 af[2];
    #pragma unroll
    for (int ks = 0; ks < 2; ++ks)
        af[ks] = *(const short8*)&X[(size_t)(qi0 + w * 16 + fr) * QKVS + h * HD + ks * 32 + kg];

    f32x4 acc[20];
    #pragma unroll
    for (int fj = 0; fj < 20; ++fj) acc[fj] = (f32x4){0.f, 0.f, 0.f, 0.f};

    #pragma unroll
    for (int fj = 0; fj < 20; ++fj) {
        int t = fj * 16 + fr;
        int tc = t < NPOS ? t : (NPOS - 1);
        #pragma unroll
        for (int ks = 0; ks < 2; ++ks) {
            short8 bp = *(const short8*)&Pt[((size_t)h * NPOS + tc) * HD + ks * 32 + kg];
            acc[fj] = __builtin_amdgcn_mfma_f32_16x16x32_bf16(af[ks], bp, acc[fj], 0, 0, 0);
        }
    }
    #pragma unroll
    for (int fj = 0; fj < 20; ++fj) {
        int t = fj * 16 + cc;
        if (t < NPOS) {
            #pragma unroll
            for (int e = 0; e < 4; ++e)
                out[((size_t)h * L_SEQ + qi0 + w * 16 + cr + e) * NPOS + t] =
                    __float2bfloat16(acc[fj][e]);
        }
    }
}

// ---------------- MFMA banded attention ----------------
__global__ __launch_bounds__(256, 2) void k_attn_mfma(const bf16* __restrict__ qb,
                                                      const bf16* __restrict__ kb,
                                                      const bf16* __restrict__ vb,
                                                      const bf16* __restrict__ c2p,
                                                      const bf16* __restrict__ p2c,
                                                      bf16* __restrict__ ctxb) {
    const int bq = blockIdx.x, h = blockIdx.y;
    const int qi0 = bq * 64, j0 = qi0 - WHALF;
    const int tid = threadIdx.x, lane = tid & 63, w = tid >> 6;
    const int fr = lane & 15, kg = (lane >> 4) << 3;
    const int cr = (lane >> 4) << 2, cc = lane & 15;

    __shared__ short KVs[20480];      // K: [320][64] swizzled; then Vt: [64][320] swizzled
    __shared__ short Ps[64][168];     // P half-buffer
    char* KVb = (char*)KVs;

    #pragma unroll
    for (int p = 0; p < 10; ++p) {
        int c = tid + p * 256;
        int t = c >> 3, d8 = (c & 7) << 3;
        int j = j0 + t;
        short8 v = {};
        if (j >= 0 && j < L_SEQ) v = *(const short8*)&kb[(size_t)j * QKVS + h * HD + d8];
        int byte = (t * 128 + d8 * 2) ^ ((t & 7) << 4);
        *(short8*)(KVb + byte) = v;
    }
    short8 aq[2];
    #pragma unroll
    for (int ks = 0; ks < 2; ++ks)
        aq[ks] = *(const short8*)&qb[(size_t)(qi0 + w * 16 + fr) * QKVS + h * HD + ks * 32 + kg];
    __syncthreads();

    f32x4 acc[20];
    #pragma unroll
    for (int fj = 0; fj < 20; ++fj) acc[fj] = (f32x4){0.f, 0.f, 0.f, 0.f};
    #pragma unroll
    for (int ks = 0; ks < 2; ++ks) {
        #pragma unroll
        for (int fj = 0; fj < 20; ++fj) {
            int t = fj * 16 + fr;
            int byte = (t * 128 + (ks * 32 + kg) * 2) ^ ((t & 7) << 4);
            short8 bk = *(const short8*)(KVb + byte);
            acc[fj] = __builtin_amdgcn_mfma_f32_16x16x32_bf16(aq[ks], bk, acc[fj], 0, 0, 0);
        }
    }
    __syncthreads();

    short8 vreg[10];
    #pragma unroll
    for (int p = 0; p < 10; ++p) {
        int c = tid + p * 256;
        int t = c >> 3, d8 = (c & 7) << 3;
        int j = j0 + t;
        short8 v = {};
        if (j >= 0 && j < L_SEQ) v = *(const short8*)&vb[(size_t)j * QKVS + h * HD + d8];
        vreg[p] = v;
    }

    const int qrel0 = w * 16 + cr;
    #pragma unroll
    for (int fj = 0; fj < 20; ++fj) {
        int t = fj * 16 + cc;
        int j = j0 + t;
        #pragma unroll
        for (int e = 0; e < 4; ++e) {
            int qr = qrel0 + e;
            bool valid = (j >= 0) && (j < L_SEQ) && (t >= qr) && (t <= qr + 256);
            float sv = -3.0e38f;
            if (valid) {
                float b1v = b2f(c2p[((size_t)h * L_SEQ + qi0 + qr) * NPOS + (t - qr)]);
                float b2v = b2f(p2c[((size_t)h * L_SEQ + j) * NPOS + (256 - t + qr)]);
                sv = acc[fj][e] + b1v + b2v;
            }
            acc[fj][e] = sv;
        }
    }

    float mx[4], sm[4];
    #pragma unroll
    for (int e = 0; e < 4; ++e) {
        float m = acc[0][e];
        #pragma unroll
        for (int fj = 1; fj < 20; ++fj) m = fmaxf(m, acc[fj][e]);
        mx[e] = m;
    }
    #pragma unroll
    for (int msk = 1; msk < 16; msk <<= 1)
        #pragma unroll
        for (int e = 0; e < 4; ++e) mx[e] = fmaxf(mx[e], __shfl_xor(mx[e], msk));
    #pragma unroll
    for (int e = 0; e < 4; ++e) sm[e] = 0.f;
    #pragma unroll
    for (int fj = 0; fj < 20; ++fj)
        #pragma unroll
        for (int e = 0; e < 4; ++e) {
            float p = __expf(acc[fj][e] - mx[e]);
            acc[fj][e] = p;
            sm[e] += p;
        }
    #pragma unroll
    for (int msk = 1; msk < 16; msk <<= 1)
        #pragma unroll
        for (int e = 0; e < 4; ++e) sm[e] += __shfl_xor(sm[e], msk);
    float rinv[4];
    #pragma unroll
    for (int e = 0; e < 4; ++e) rinv[e] = 1.0f / sm[e];

    #pragma unroll
    for (int p = 0; p < 10; ++p) {
        int c = tid + p * 256;
        int t = c >> 3, d8 = (c & 7) << 3;
        #pragma unroll
        for (int e = 0; e < 8; ++e) {
            int d = d8 + e;
            int byte = (d * 640 + t * 2) ^ ((d & 7) << 4);
            *(short*)(KVb + byte) = vreg[p][e];
        }
    }
    #pragma unroll
    for (int fj = 0; fj < 10; ++fj) {
        int col = fj * 16 + cc;
        #pragma unroll
        for (int e = 0; e < 4; ++e)
            Ps[w * 16 + cr + e][col] = f2bs(acc[fj][e]);
    }
    __syncthreads();

    f32x4 acc2[4];
    #pragma unroll
    for (int f = 0; f < 4; ++f) acc2[f] = (f32x4){0.f, 0.f, 0.f, 0.f};
    #pragma unroll
    for (int ks = 0; ks < 5; ++ks) {
        short8 pa = *(const short8*)&Ps[w * 16 + fr][ks * 32 + kg];
        #pragma unroll
        for (int f = 0; f < 4; ++f) {
            int d = f * 16 + fr;
            int tg = ks * 32 + kg;
            int byte = (d * 640 + tg * 2) ^ ((d & 7) << 4);
            short8 bv = *(const short8*)(KVb + byte);
            acc2[f] = __builtin_amdgcn_mfma_f32_16x16x32_bf16(pa, bv, acc2[f], 0, 0, 0);
        }
    }
    #pragma unroll
    for (int fj = 10; fj < 20; ++fj) {
        int col = (fj - 10) * 16 + cc;
        #pragma unroll
        for (int e = 0; e < 4; ++e)
            Ps[w * 16 + cr + e][col] = f2bs(acc[fj][e]);
    }
    #pragma unroll
    for (int ks = 0; ks < 5; ++ks) {
        short8 pa = *(const short8*)&Ps[w * 16 + fr][ks * 32 + kg];
        #pragma unroll
        for (int f = 0; f < 4; ++f) {
            int d = f * 16 + fr;
            int tg = 160 + ks * 32 + kg;
            int byte = (d * 640 + tg * 2) ^ ((d & 7) << 4);
            short8 bv = *(const short8*)(KVb + byte);
            acc2[f] = __builtin_amdgcn_mfma_f32_16x16x32_bf16(pa, bv, acc2[f], 0, 0, 0);
        }
    }

    #pragma unroll
    for (int f = 0; f < 4; ++f)
        #pragma unroll
        for (int e = 0; e < 4; ++e) {
            int row = qi0 + w * 16 + cr + e;
            int d = f * 16 + cc;
            ctxb[(size_t)row * HID_ + h * HD + d] = __float2bfloat16(acc2[f][e] * rinv[e]);
        }
}

// ---------------- launch ----------------
extern "C" void kernel_launch(void* const* d_in, const int* in_sizes, int n_in,
                              void* d_out, int out_size, void* d_ws, size_t ws_size,
                              hipStream_t stream) {
    const float* hid  = (const float*)d_in[0];
    const float* wq   = (const float*)d_in[2];
    const float* wk   = (const float*)d_in[3];
    const float* wv   = (const float*)d_in[4];
    const float* pk   = (const float*)d_in[5];
    const float* pq   = (const float*)d_in[6];
    const float* wo   = (const float*)d_in[7];
    const float* bo   = (const float*)d_in[8];
    const float* ln1g = (const float*)d_in[9];
    const float* ln1b = (const float*)d_in[10];
    const float* ln2g = (const float*)d_in[11];
    const float* ln2b = (const float*)d_in[12];
    const float* w1   = (const float*)d_in[13];
    const float* b1   = (const float*)d_in[14];
    const float* w2   = (const float*)d_in[15];
    const float* b2   = (const float*)d_in[16];
    float* out = (float*)d_out;

    char* ws = (char*)d_ws;
    size_t off = 0;
    auto alloc = [&](size_t bytes) -> void* {
        void* p = ws + off;
        off += (bytes + 255) & ~(size_t)255;
        return p;
    };
    bf16* wqkvb = (bf16*)alloc((size_t)QKVS * HID_ * 2);   // [3072][1024]
    bf16* wob   = (bf16*)alloc((size_t)HID_ * HID_ * 2);
    bf16* w1b   = (bf16*)alloc((size_t)HID_ * FF_ * 2);    // [4096][1024]
    bf16* w2b   = (bf16*)alloc((size_t)HID_ * FF_ * 2);    // [1024][4096]
    bf16* pkt   = (bf16*)alloc((size_t)NH * NPOS * HD * 2);
    bf16* pqt   = (bf16*)alloc((size_t)NH * NPOS * HD * 2);
    bf16* x1b   = (bf16*)alloc((size_t)L_SEQ * HID_ * 2);
    bf16* qkv   = (bf16*)alloc((size_t)L_SEQ * QKVS * 2);  // [2048][3072]
    bf16* c2p   = (bf16*)alloc((size_t)NH * L_SEQ * NPOS * 2);
    bf16* p2c   = (bf16*)alloc((size_t)NH * L_SEQ * NPOS * 2);
    bf16* ctxb  = (bf16*)alloc((size_t)L_SEQ * HID_ * 2);
    float* hbuf = (float*)alloc((size_t)L_SEQ * HID_ * 4);
    bf16* x2b   = (bf16*)alloc((size_t)L_SEQ * HID_ * 2);
    bf16* ffb   = (bf16*)alloc((size_t)L_SEQ * FF_ * 2);   // 16 MB
    (void)ws_size; (void)in_sizes; (void)n_in; (void)out_size;

    float* wopart  = (float*)ffb;   // 2*2048*1024*4 = 16 MB, dead before FF1 writes ffb
    float* ff2part = (float*)c2p;   // 4*2048*1024*4 = 32 MB <= c2p+p2c (33.6 MB), dead after attn

    // weight conversions (coalesced tiled transpose to [N][K])
    k_transpose_tiled<<<dim3(16, 16), 256, 0, stream>>>(wq, wqkvb, 1024, 1024);
    k_transpose_tiled<<<dim3(16, 16), 256, 0, stream>>>(wk, wqkvb + (size_t)1024 * 1024, 1024, 1024);
    k_transpose_tiled<<<dim3(16, 16), 256, 0, stream>>>(wv, wqkvb + (size_t)2048 * 1024, 1024, 1024);
    k_transpose_tiled<<<dim3(16, 16), 256, 0, stream>>>(wo, wob, 1024, 1024);
    k_transpose_tiled<<<dim3(16, 64), 256, 0, stream>>>(w1, w1b, 1024, 4096);
    k_transpose_tiled<<<dim3(64, 16), 256, 0, stream>>>(w2, w2b, 4096, 1024);
    k_pos_transpose<<<1028, 256, 0, stream>>>(pk, pkt);
    k_pos_transpose<<<1028, 256, 0, stream>>>(pq, pqt);

    // LN1
    k_layernorm<<<L_SEQ, 256, 0, stream>>>(hid, ln1g, ln1b, x1b);

    const int MN = L_SEQ * HID_;
    // fused QKV projection: [2048][1024] x [3072][1024]^T -> qkv
    k_gemm64<0><<<dim3(32, 24, 1), 256, 0, stream>>>(x1b, wqkvb, qkv, nullptr, nullptr, QKVS, HID_, 32, MN);

    // relative position tables
    dim3 g_rp(L_SEQ / 64, NH);
    k_relpos_mfma<<<g_rp, 256, 0, stream>>>(qkv, pkt, c2p);
    k_relpos_mfma<<<g_rp, 256, 0, stream>>>(qkv + 1024, pqt, p2c);

    // banded attention
    k_attn_mfma<<<dim3(L_SEQ / 64, NH), 256, 0, stream>>>(qkv, qkv + 1024, qkv + 2048, c2p, p2c, ctxb);

    // Wo (split-K=2) + reduce(bias+residual) -> hbuf
    k_gemm64<3><<<dim3(32, 8, 2), 256, 0, stream>>>(ctxb, wob, nullptr, wopart, nullptr, HID_, HID_, 16, MN);
    k_reduce<2><<<2048, 256, 0, stream>>>(wopart, bo, hid, hbuf);

    // LN2
    k_layernorm<<<L_SEQ, 256, 0, stream>>>(hbuf, ln2g, ln2b, x2b);

    // FF1: gelu(x2 @ w1 + b1) -> ffb
    k_gemm64<2><<<dim3(32, 32, 1), 256, 0, stream>>>(x2b, w1b, ffb, nullptr, b1, FF_, HID_, 32, MN);

    // FF2 (split-K=4) + reduce(bias+residual) -> out
    k_gemm64<3><<<dim3(32, 8, 4), 256, 0, stream>>>(ffb, w2b, nullptr, ff2part, nullptr, HID_, FF_, 32, MN);
    k_reduce<4><<<2048, 256, 0, stream>>>(ff2part, b2, hbuf, out);
}

// Round 6
// 339.871 us; speedup vs baseline: 3.0654x; 1.0031x over previous
//
#include <hip/hip_runtime.h>
#include <hip/hip_bf16.h>
#include <cstdint>

typedef __hip_bfloat16 bf16;
typedef __attribute__((ext_vector_type(8))) short short8;
typedef __attribute__((ext_vector_type(4))) float f32x4;
typedef __attribute__((address_space(1))) const unsigned int gu32;
typedef __attribute__((address_space(3))) unsigned int lu32;

#define L_SEQ 2048
#define HID_  1024
#define NH    16
#define HD    64
#define FF_   4096
#define NPOS  257   // 2W+1
#define WHALF 128
#define QKVS  3072  // fused qkv row stride
#define NTILE 32    // L_SEQ/64
#define BT_TILE (320 * 64)   // shorts per (h,tile) bias tile

__device__ inline float b2f(bf16 v) { return __bfloat162float(v); }
__device__ inline short f2bs(float f) {
    bf16 b = __float2bfloat16(f);
    return *reinterpret_cast<short*>(&b);
}

// ---------------- tiled transpose-convert: src fp32 [K][N] -> dst bf16 [N][K] ----------------
__global__ __launch_bounds__(256) void k_transpose_tiled(const float* __restrict__ src,
                                                         bf16* __restrict__ dst,
                                                         int K, int N) {
    const int k0 = blockIdx.x * 64, n0 = blockIdx.y * 64;
    __shared__ float t[64][65];
    const int c = threadIdx.x & 63, r4 = threadIdx.x >> 6;
    #pragma unroll
    for (int i = 0; i < 16; ++i)
        t[i * 4 + r4][c] = src[(size_t)(k0 + i * 4 + r4) * N + n0 + c];
    __syncthreads();
    #pragma unroll
    for (int i = 0; i < 16; ++i) {
        int n = i * 4 + r4;
        dst[(size_t)(n0 + n) * K + k0 + c] = __float2bfloat16(t[c][n]);
    }
}

// pos [H][64][257] fp32 -> Pt [H][257][64] bf16
__global__ void k_pos_transpose(const float* __restrict__ src, bf16* __restrict__ dst) {
    const int total = NH * NPOS * HD;
    for (int idx = blockIdx.x * blockDim.x + threadIdx.x; idx < total;
         idx += gridDim.x * blockDim.x) {
        int d = idx & 63;
        int r = idx >> 6;
        int t = r % NPOS;
        int h = r / NPOS;
        dst[idx] = __float2bfloat16(src[((size_t)h * HD + d) * NPOS + t]);
    }
}

// ---------------- layernorm ----------------
__global__ __launch_bounds__(256) void k_layernorm(const float* __restrict__ x,
                                                   const float* __restrict__ g,
                                                   const float* __restrict__ b,
                                                   bf16* __restrict__ out) {
    const int row = blockIdx.x, tid = threadIdx.x;
    const int lane = tid & 63, w = tid >> 6;
    const float4 v = *(const float4*)(x + (size_t)row * HID_ + tid * 4);
    float vals[4] = {v.x, v.y, v.z, v.w};
    float s = vals[0] + vals[1] + vals[2] + vals[3];
    float ss = vals[0]*vals[0] + vals[1]*vals[1] + vals[2]*vals[2] + vals[3]*vals[3];
    for (int off = 32; off; off >>= 1) { s += __shfl_down(s, off); ss += __shfl_down(ss, off); }
    __shared__ float rs[4], rss[4], mv[2];
    if (lane == 0) { rs[w] = s; rss[w] = ss; }
    __syncthreads();
    if (tid == 0) {
        float S = rs[0] + rs[1] + rs[2] + rs[3];
        float SS = rss[0] + rss[1] + rss[2] + rss[3];
        float mean = S * (1.0f / HID_);
        float var = SS * (1.0f / HID_) - mean * mean;
        mv[0] = mean; mv[1] = rsqrtf(var + 1e-8f);
    }
    __syncthreads();
    const float mean = mv[0], rstd = mv[1];
    #pragma unroll
    for (int e = 0; e < 4; ++e) {
        int c = tid * 4 + e;
        out[(size_t)row * HID_ + c] = __float2bfloat16((vals[e] - mean) * rstd * g[c] + b[c]);
    }
}

// ---------------- bf16 MFMA GEMM, 64x128 tile, global_load_lds + 2-phase dbuf ----------------
template <int EPI>
__global__ __launch_bounds__(256) void k_gemm64(const bf16* __restrict__ A,
                                                const bf16* __restrict__ B,
                                                bf16* __restrict__ outB,
                                                float* __restrict__ outF,
                                                const float* __restrict__ bias,
                                                int N, int K, int kTiles, int MN) {
    __shared__ __align__(16) short As[2][2048];   // [64][32] swizzled
    __shared__ __align__(16) short Bs[2][4096];   // [128][32] swizzled
    const int tid = threadIdx.x;
    const int bm = blockIdx.x * 64, bn = blockIdx.y * 128;
    const int lane = tid & 63, w = tid >> 6;
    const int wr = w >> 1, wc = w & 1;            // wave tile: 32 x 64
    const int k0base = blockIdx.z * kTiles * 32;

    const int crow = lane >> 2;
    const int c16p = lane & 3;
    const int coll = (c16p ^ (crow & 3)) * 8;
    const short* Ag = (const short*)A;
    const short* Bg = (const short*)B;
    const size_t a_off = (size_t)(bm + w * 16 + crow) * K + coll;
    const size_t b_off0 = (size_t)(bn + w * 32 + crow) * K + coll;
    const size_t b_off1 = (size_t)(bn + w * 32 + 16 + crow) * K + coll;

    auto stage = [&](int buf, int k0) {
        __builtin_amdgcn_global_load_lds((gu32*)(Ag + a_off + k0), (lu32*)&As[buf][w * 512], 16, 0, 0);
        __builtin_amdgcn_global_load_lds((gu32*)(Bg + b_off0 + k0), (lu32*)&Bs[buf][w * 1024], 16, 0, 0);
        __builtin_amdgcn_global_load_lds((gu32*)(Bg + b_off1 + k0), (lu32*)&Bs[buf][w * 1024 + 512], 16, 0, 0);
    };

    const int fr = lane & 15, kq = lane >> 4;
    const int xbyte = ((kq ^ (fr & 3)) << 4);

    f32x4 acc[2][4] = {};
    stage(0, k0base);
    __syncthreads();

    for (int t = 0; t < kTiles; ++t) {
        if (t + 1 < kTiles) stage((t + 1) & 1, k0base + (t + 1) * 32);
        const char* Ab = (const char*)As[t & 1];
        const char* Bb = (const char*)Bs[t & 1];
        short8 af[2], bfv[4];
        #pragma unroll
        for (int m2 = 0; m2 < 2; ++m2)
            af[m2] = *(const short8*)(Ab + ((wr * 32 + m2 * 16 + fr) << 6) + xbyte);
        #pragma unroll
        for (int n2 = 0; n2 < 4; ++n2)
            bfv[n2] = *(const short8*)(Bb + ((wc * 64 + n2 * 16 + fr) << 6) + xbyte);
        #pragma unroll
        for (int m2 = 0; m2 < 2; ++m2)
            #pragma unroll
            for (int n2 = 0; n2 < 4; ++n2)
                acc[m2][n2] = __builtin_amdgcn_mfma_f32_16x16x32_bf16(af[m2], bfv[n2], acc[m2][n2], 0, 0, 0);
        __syncthreads();
    }

    const int cr = kq * 4, cc = fr;
    #pragma unroll
    for (int m2 = 0; m2 < 2; ++m2) {
        #pragma unroll
        for (int n2 = 0; n2 < 4; ++n2) {
            const int col = bn + wc * 64 + n2 * 16 + cc;
            #pragma unroll
            for (int e = 0; e < 4; ++e) {
                const int row = bm + wr * 32 + m2 * 16 + cr + e;
                const size_t o = (size_t)row * N + col;
                float v = acc[m2][n2][e];
                if (EPI == 0) {
                    outB[o] = __float2bfloat16(v);
                } else if (EPI == 2) {
                    float xg = v + bias[col];
                    float gl = 0.5f * xg * (1.0f + erff(xg * 0.70710678f));
                    outB[o] = __float2bfloat16(gl);
                } else {
                    outF[(size_t)blockIdx.z * MN + o] = v;
                }
            }
        }
    }
}

// ---------------- split-K reduce + bias + residual (N=1024, M=2048) ----------------
template <int S>
__global__ __launch_bounds__(256) void k_reduce(const float* __restrict__ parts,
                                                const float* __restrict__ bias,
                                                const float* __restrict__ res,
                                                float* __restrict__ out) {
    const int idx = blockIdx.x * 256 + threadIdx.x;
    const float4* p = (const float4*)parts;
    float4 s = p[idx];
    #pragma unroll
    for (int ss = 1; ss < S; ++ss) {
        float4 t2 = p[idx + (size_t)ss * 524288];
        s.x += t2.x; s.y += t2.y; s.z += t2.z; s.w += t2.w;
    }
    float4 bb = ((const float4*)bias)[idx & 255];
    float4 rr = ((const float4*)res)[idx];
    float4 o = {s.x + bb.x + rr.x, s.y + bb.y + rr.y, s.z + bb.z + rr.z, s.w + bb.w + rr.w};
    ((float4*)out)[idx] = o;
}

// ---------------- relpos -> band-aligned transposed bias tables ----------------
// MODE 0 (c2p from Q): value c2p[i][p] -> BT[h][bq][t=p+il][il],  i = bq*64+il
// MODE 1 (p2c from K): value p2c[j][u] -> BT[h][bq][t=j-64bq+128][il=(j+u-128)&63]
template <int MODE>
__global__ __launch_bounds__(256) void k_relpos_bt(const bf16* __restrict__ X,
                                                   const bf16* __restrict__ Pt,
                                                   bf16* __restrict__ bt) {
    const int bq = blockIdx.x, h = blockIdx.y;
    const int r0 = bq * 64;
    const int tid = threadIdx.x, lane = tid & 63, w = tid >> 6;
    const int fr = lane & 15, kg = (lane >> 4) << 3;
    const int cr = (lane >> 4) << 2, cc = lane & 15;

    short8 af[2];
    #pragma unroll
    for (int ks = 0; ks < 2; ++ks)
        af[ks] = *(const short8*)&X[(size_t)(r0 + w * 16 + fr) * QKVS + h * HD + ks * 32 + kg];

    f32x4 acc[20];
    #pragma unroll
    for (int fj = 0; fj < 20; ++fj) acc[fj] = (f32x4){0.f, 0.f, 0.f, 0.f};

    #pragma unroll
    for (int fj = 0; fj < 20; ++fj) {
        int p = fj * 16 + fr;
        int pc = p < NPOS ? p : (NPOS - 1);
        #pragma unroll
        for (int ks = 0; ks < 2; ++ks) {
            short8 bp = *(const short8*)&Pt[((size_t)h * NPOS + pc) * HD + ks * 32 + kg];
            acc[fj] = __builtin_amdgcn_mfma_f32_16x16x32_bf16(af[ks], bp, acc[fj], 0, 0, 0);
        }
    }

    #pragma unroll
    for (int fj = 0; fj < 20; ++fj) {
        int p = fj * 16 + cc;            // MODE0: pos index; MODE1: u
        if (p < NPOS) {
            #pragma unroll
            for (int e = 0; e < 4; ++e) {
                int rloc = w * 16 + cr + e;   // MODE0: il; MODE1: j - r0
                if (MODE == 0) {
                    int t = p + rloc;
                    bt[((size_t)(h * NTILE + bq) * 320 + t) * 64 + rloc] =
                        __float2bfloat16(acc[fj][e]);
                } else {
                    int j = r0 + rloc;
                    int s = j + p - 128;
                    if (s >= 0 && s < L_SEQ) {
                        int tb = s >> 6, il = s & 63;
                        int t = j - tb * 64 + 128;
                        bt[((size_t)(h * NTILE + tb) * 320 + t) * 64 + il] =
                            __float2bfloat16(acc[fj][e]);
                    }
                }
            }
        }
    }
}

// ---------------- MFMA banded attention (bias via identity-MFMA) ----------------
__global__ __launch_bounds__(256, 3) void k_attn_mfma(const bf16* __restrict__ qb,
                                                      const bf16* __restrict__ kb,
                                                      const bf16* __restrict__ vb,
                                                      const bf16* __restrict__ bt1,
                                                      const bf16* __restrict__ bt2,
                                                      bf16* __restrict__ ctxb) {
    const int bq = blockIdx.x, h = blockIdx.y;
    const int qi0 = bq * 64, j0 = qi0 - WHALF;
    const int tid = threadIdx.x, lane = tid & 63, w = tid >> 6;
    const int fr = lane & 15, kq = lane >> 4, kg = kq << 3;
    const int cr = kq << 2, cc = fr;

    __shared__ short KVs[20480];            // K: [320][64] swizzled; then Vt: [64][320] swizzled
    __shared__ __align__(16) short Ps[64][72];  // P chunk buffer (64 cols + pad)
    char* KVb = (char*)KVs;

    // ---- stage K window into LDS (swizzled) ----
    #pragma unroll
    for (int p = 0; p < 10; ++p) {
        int c = tid + p * 256;
        int t = c >> 3, d8 = (c & 7) << 3;
        int j = j0 + t;
        short8 v = {};
        if (j >= 0 && j < L_SEQ) v = *(const short8*)&kb[(size_t)j * QKVS + h * HD + d8];
        int byte = (t * 128 + d8 * 2) ^ ((t & 7) << 4);
        *(short8*)(KVb + byte) = v;
    }
    short8 aq[2];
    #pragma unroll
    for (int ks = 0; ks < 2; ++ks)
        aq[ks] = *(const short8*)&qb[(size_t)(qi0 + w * 16 + fr) * QKVS + h * HD + ks * 32 + kg];

    // identity A-fragment (A = [I16 | 0])
    short8 ifrag = {};
    {
        int d = fr - kg;
        if (d >= 0 && d < 8) ifrag[d] = (short)0x3F80;
    }
    __syncthreads();

    // ---- S = Q @ K^T ----
    f32x4 acc[20];
    #pragma unroll
    for (int fj = 0; fj < 20; ++fj) acc[fj] = (f32x4){0.f, 0.f, 0.f, 0.f};
    #pragma unroll
    for (int ks = 0; ks < 2; ++ks) {
        #pragma unroll
        for (int fj = 0; fj < 20; ++fj) {
            int t = fj * 16 + fr;
            int byte = (t * 128 + (ks * 32 + kg) * 2) ^ ((t & 7) << 4);
            short8 bk = *(const short8*)(KVb + byte);
            acc[fj] = __builtin_amdgcn_mfma_f32_16x16x32_bf16(aq[ks], bk, acc[fj], 0, 0, 0);
        }
    }
    __syncthreads();   // all waves done reading K region

    // ---- prefetch V into registers ----
    short8 vreg[10];
    #pragma unroll
    for (int p = 0; p < 10; ++p) {
        int c = tid + p * 256;
        int t = c >> 3, d8 = (c & 7) << 3;
        int j = j0 + t;
        short8 v = {};
        if (j >= 0 && j < L_SEQ) v = *(const short8*)&vb[(size_t)j * QKVS + h * HD + d8];
        vreg[p] = v;
    }

    // ---- add biases via identity-MFMA (one b128 load per table per fragment) ----
    {
        const short* t1 = (const short*)bt1 + (size_t)(h * NTILE + bq) * BT_TILE;
        const short* t2 = (const short*)bt2 + (size_t)(h * NTILE + bq) * BT_TILE;
        #pragma unroll
        for (int fj = 0; fj < 20; ++fj) {
            int off = (fj * 16 + fr) * 64 + w * 16 + kg;
            short8 b1 = *(const short8*)(t1 + off);
            short8 b2 = *(const short8*)(t2 + off);
            acc[fj] = __builtin_amdgcn_mfma_f32_16x16x32_bf16(ifrag, b1, acc[fj], 0, 0, 0);
            acc[fj] = __builtin_amdgcn_mfma_f32_16x16x32_bf16(ifrag, b2, acc[fj], 0, 0, 0);
        }
    }

    // ---- band mask ----
    const int qrel0 = w * 16 + cr;
    #pragma unroll
    for (int fj = 0; fj < 20; ++fj) {
        int t = fj * 16 + cc;
        int j = j0 + t;
        #pragma unroll
        for (int e = 0; e < 4; ++e) {
            int qr = qrel0 + e;
            bool valid = (j >= 0) && (j < L_SEQ) && (t >= qr) && (t <= qr + 256);
            acc[fj][e] = valid ? acc[fj][e] : -3.0e38f;
        }
    }

    // ---- in-wave row softmax ----
    float mx[4], sm[4];
    #pragma unroll
    for (int e = 0; e < 4; ++e) {
        float m = acc[0][e];
        #pragma unroll
        for (int fj = 1; fj < 20; ++fj) m = fmaxf(m, acc[fj][e]);
        mx[e] = m;
    }
    #pragma unroll
    for (int msk = 1; msk < 16; msk <<= 1)
        #pragma unroll
        for (int e = 0; e < 4; ++e) mx[e] = fmaxf(mx[e], __shfl_xor(mx[e], msk));
    #pragma unroll
    for (int e = 0; e < 4; ++e) sm[e] = 0.f;
    #pragma unroll
    for (int fj = 0; fj < 20; ++fj)
        #pragma unroll
        for (int e = 0; e < 4; ++e) {
            float p = __expf(acc[fj][e] - mx[e]);
            acc[fj][e] = p;
            sm[e] += p;
        }
    #pragma unroll
    for (int msk = 1; msk < 16; msk <<= 1)
        #pragma unroll
        for (int e = 0; e < 4; ++e) sm[e] += __shfl_xor(sm[e], msk);
    float rinv[4];
    #pragma unroll
    for (int e = 0; e < 4; ++e) rinv[e] = 1.0f / sm[e];

    // ---- write Vt (transposed, swizzled) into the K region ----
    #pragma unroll
    for (int p = 0; p < 10; ++p) {
        int c = tid + p * 256;
        int t = c >> 3, d8 = (c & 7) << 3;
        #pragma unroll
        for (int e = 0; e < 8; ++e) {
            int d = d8 + e;
            int byte = (d * 640 + t * 2) ^ ((d & 7) << 4);
            *(short*)(KVb + byte) = vreg[p][e];
        }
    }

    // ---- PV in 5 chunks of 64 cols; P rows are wave-private (no barrier after ch0) ----
    f32x4 acc2[4];
    #pragma unroll
    for (int f = 0; f < 4; ++f) acc2[f] = (f32x4){0.f, 0.f, 0.f, 0.f};
    #pragma unroll
    for (int ch = 0; ch < 5; ++ch) {
        #pragma unroll
        for (int fjl = 0; fjl < 4; ++fjl) {
            int fj = ch * 4 + fjl;
            int col = fjl * 16 + cc;
            #pragma unroll
            for (int e = 0; e < 4; ++e)
                Ps[w * 16 + cr + e][col] = f2bs(acc[fj][e]);
        }
        if (ch == 0) __syncthreads();   // Vt + first P chunk visible
        #pragma unroll
        for (int ks2 = 0; ks2 < 2; ++ks2) {
            short8 pa = *(const short8*)&Ps[w * 16 + fr][ks2 * 32 + kg];
            #pragma unroll
            for (int f = 0; f < 4; ++f) {
                int d = f * 16 + fr;
                int tg = ch * 64 + ks2 * 32 + kg;
                int byte = (d * 640 + tg * 2) ^ ((d & 7) << 4);
                short8 bv = *(const short8*)(KVb + byte);
                acc2[f] = __builtin_amdgcn_mfma_f32_16x16x32_bf16(pa, bv, acc2[f], 0, 0, 0);
            }
        }
    }

    // ---- epilogue ----
    #pragma unroll
    for (int f = 0; f < 4; ++f)
        #pragma unroll
        for (int e = 0; e < 4; ++e) {
            int row = qi0 + w * 16 + cr + e;
            int d = f * 16 + cc;
            ctxb[(size_t)row * HID_ + h * HD + d] = __float2bfloat16(acc2[f][e] * rinv[e]);
        }
}

// ---------------- launch ----------------
extern "C" void kernel_launch(void* const* d_in, const int* in_sizes, int n_in,
                              void* d_out, int out_size, void* d_ws, size_t ws_size,
                              hipStream_t stream) {
    const float* hid  = (const float*)d_in[0];
    const float* wq   = (const float*)d_in[2];
    const float* wk   = (const float*)d_in[3];
    const float* wv   = (const float*)d_in[4];
    const float* pk   = (const float*)d_in[5];
    const float* pq   = (const float*)d_in[6];
    const float* wo   = (const float*)d_in[7];
    const float* bo   = (const float*)d_in[8];
    const float* ln1g = (const float*)d_in[9];
    const float* ln1b = (const float*)d_in[10];
    const float* ln2g = (const float*)d_in[11];
    const float* ln2b = (const float*)d_in[12];
    const float* w1   = (const float*)d_in[13];
    const float* b1   = (const float*)d_in[14];
    const float* w2   = (const float*)d_in[15];
    const float* b2   = (const float*)d_in[16];
    float* out = (float*)d_out;

    char* ws = (char*)d_ws;
    size_t off = 0;
    auto alloc = [&](size_t bytes) -> void* {
        void* p = ws + off;
        off += (bytes + 255) & ~(size_t)255;
        return p;
    };
    const size_t BT_BYTES = (size_t)NH * NTILE * BT_TILE * 2 + 256;  // ~21 MB + pad
    bf16* wqkvb = (bf16*)alloc((size_t)QKVS * HID_ * 2);   // [3072][1024]
    bf16* wob   = (bf16*)alloc((size_t)HID_ * HID_ * 2);
    bf16* w1b   = (bf16*)alloc((size_t)HID_ * FF_ * 2);    // [4096][1024]
    bf16* w2b   = (bf16*)alloc((size_t)HID_ * FF_ * 2);    // [1024][4096]
    bf16* pkt   = (bf16*)alloc((size_t)NH * NPOS * HD * 2);
    bf16* pqt   = (bf16*)alloc((size_t)NH * NPOS * HD * 2);
    bf16* x1b   = (bf16*)alloc((size_t)L_SEQ * HID_ * 2);
    bf16* qkv   = (bf16*)alloc((size_t)L_SEQ * QKVS * 2);  // 12.6 MB
    bf16* bt1   = (bf16*)alloc(BT_BYTES);                  // band-aligned c2p
    bf16* bt2   = (bf16*)alloc(BT_BYTES);                  // band-aligned p2c
    bf16* ctxb  = (bf16*)alloc((size_t)L_SEQ * HID_ * 2);
    float* hbuf = (float*)alloc((size_t)L_SEQ * HID_ * 4);
    bf16* x2b   = (bf16*)alloc((size_t)L_SEQ * HID_ * 2);
    bf16* ffb   = (bf16*)alloc((size_t)L_SEQ * FF_ * 2);   // 16 MB
    (void)ws_size; (void)in_sizes; (void)n_in; (void)out_size;

    float* wopart  = (float*)ffb;   // 16 MB; dead before FF1 writes ffb
    float* ff2part = (float*)qkv;   // 32 MB over qkv+bt1 (33.6 MB), both dead after attn

    // weight conversions (coalesced tiled transpose to [N][K])
    k_transpose_tiled<<<dim3(16, 16), 256, 0, stream>>>(wq, wqkvb, 1024, 1024);
    k_transpose_tiled<<<dim3(16, 16), 256, 0, stream>>>(wk, wqkvb + (size_t)1024 * 1024, 1024, 1024);
    k_transpose_tiled<<<dim3(16, 16), 256, 0, stream>>>(wv, wqkvb + (size_t)2048 * 1024, 1024, 1024);
    k_transpose_tiled<<<dim3(16, 16), 256, 0, stream>>>(wo, wob, 1024, 1024);
    k_transpose_tiled<<<dim3(16, 64), 256, 0, stream>>>(w1, w1b, 1024, 4096);
    k_transpose_tiled<<<dim3(64, 16), 256, 0, stream>>>(w2, w2b, 4096, 1024);
    k_pos_transpose<<<1028, 256, 0, stream>>>(pk, pkt);
    k_pos_transpose<<<1028, 256, 0, stream>>>(pq, pqt);

    // LN1
    k_layernorm<<<L_SEQ, 256, 0, stream>>>(hid, ln1g, ln1b, x1b);

    const int MN = L_SEQ * HID_;
    // fused QKV projection
    k_gemm64<0><<<dim3(32, 24, 1), 256, 0, stream>>>(x1b, wqkvb, qkv, nullptr, nullptr, QKVS, HID_, 32, MN);

    // band-aligned bias tables
    dim3 g_rp(NTILE, NH);
    k_relpos_bt<0><<<g_rp, 256, 0, stream>>>(qkv, pkt, bt1);
    k_relpos_bt<1><<<g_rp, 256, 0, stream>>>(qkv + 1024, pqt, bt2);

    // banded attention
    k_attn_mfma<<<dim3(NTILE, NH), 256, 0, stream>>>(qkv, qkv + 1024, qkv + 2048, bt1, bt2, ctxb);

    // Wo (split-K=2) + reduce(bias+residual) -> hbuf
    k_gemm64<3><<<dim3(32, 8, 2), 256, 0, stream>>>(ctxb, wob, nullptr, wopart, nullptr, HID_, HID_, 16, MN);
    k_reduce<2><<<2048, 256, 0, stream>>>(wopart, bo, hid, hbuf);

    // LN2
    k_layernorm<<<L_SEQ, 256, 0, stream>>>(hbuf, ln2g, ln2b, x2b);

    // FF1: gelu(x2 @ w1 + b1) -> ffb
    k_gemm64<2><<<dim3(32, 32, 1), 256, 0, stream>>>(x2b, w1b, ffb, nullptr, b1, FF_, HID_, 32, MN);

    // FF2 (split-K=4) + reduce(bias+residual) -> out
    k_gemm64<3><<<dim3(32, 8, 4), 256, 0, stream>>>(ffb, w2b, nullptr, ff2part, nullptr, HID_, FF_, 32, MN);
    k_reduce<4><<<2048, 256, 0, stream>>>(ff2part, b2, hbuf, out);
}

// Round 7
// 327.030 us; speedup vs baseline: 3.1858x; 1.0393x over previous
//
#include <hip/hip_runtime.h>
#include <hip/hip_bf16.h>
#include <cstdint>

typedef __hip_bfloat16 bf16;
typedef __attribute__((ext_vector_type(8))) short short8;
typedef __attribute__((ext_vector_type(4))) float f32x4;
typedef __attribute__((address_space(1))) const unsigned int gu32;
typedef __attribute__((address_space(3))) unsigned int lu32;

#define L_SEQ 2048
#define HID_  1024
#define NH    16
#define HD    64
#define FF_   4096
#define NPOS  257   // 2W+1
#define WHALF 128
#define QKVS  3072  // fused qkv row stride
#define NTILE 32    // L_SEQ/64
#define BT_TILE (320 * 64)   // shorts per (h,tile) bias tile

__device__ inline short f2bs(float f) {
    bf16 b = __float2bfloat16(f);
    return *reinterpret_cast<short*>(&b);
}

// ---------------- merged weight transpose-convert: 6 weights, fp32 [K][N] -> bf16 [N][K] ----
__global__ __launch_bounds__(256) void k_wt_all(const float* __restrict__ wq,
                                                const float* __restrict__ wk,
                                                const float* __restrict__ wv,
                                                const float* __restrict__ wo,
                                                const float* __restrict__ w1,
                                                const float* __restrict__ w2,
                                                bf16* __restrict__ wqkvb,
                                                bf16* __restrict__ wob,
                                                bf16* __restrict__ w1b,
                                                bf16* __restrict__ w2b) {
    const int id = blockIdx.x;
    const float* src; bf16* dst; int K, N, tile;
    if (id < 768)       { int s = id >> 8; tile = id & 255;
                          src = s == 0 ? wq : (s == 1 ? wk : wv);
                          dst = wqkvb + (size_t)s * 1024 * 1024; K = 1024; N = 1024; }
    else if (id < 1024) { tile = id - 768;  src = wo; dst = wob; K = 1024; N = 1024; }
    else if (id < 2048) { tile = id - 1024; src = w1; dst = w1b; K = 1024; N = 4096; }
    else                { tile = id - 2048; src = w2; dst = w2b; K = 4096; N = 1024; }
    const int ktiles = K >> 6;
    const int k0 = (tile % ktiles) * 64, n0 = (tile / ktiles) * 64;

    __shared__ float t[64][65];
    const int c = threadIdx.x & 63, r4 = threadIdx.x >> 6;
    #pragma unroll
    for (int i = 0; i < 16; ++i)
        t[i * 4 + r4][c] = src[(size_t)(k0 + i * 4 + r4) * N + n0 + c];
    __syncthreads();
    #pragma unroll
    for (int i = 0; i < 16; ++i) {
        int n = i * 4 + r4;
        dst[(size_t)(n0 + n) * K + k0 + c] = __float2bfloat16(t[c][n]);
    }
}

// pos [H][64][257] fp32 -> Pt [H][257][64] bf16, both tables in one launch
__global__ void k_pos2(const float* __restrict__ pk, const float* __restrict__ pq,
                       bf16* __restrict__ pkt, bf16* __restrict__ pqt) {
    const int T = NH * NPOS * HD;
    for (int gi = blockIdx.x * blockDim.x + threadIdx.x; gi < 2 * T;
         gi += gridDim.x * blockDim.x) {
        const float* src = gi < T ? pk : pq;
        bf16* dst = gi < T ? pkt : pqt;
        int idx = gi < T ? gi : gi - T;
        int d = idx & 63;
        int r = idx >> 6;
        int t = r % NPOS;
        int h = r / NPOS;
        dst[idx] = __float2bfloat16(src[((size_t)h * HD + d) * NPOS + t]);
    }
}

// ---------------- layernorm ----------------
__global__ __launch_bounds__(256) void k_layernorm(const float* __restrict__ x,
                                                   const float* __restrict__ g,
                                                   const float* __restrict__ b,
                                                   bf16* __restrict__ out) {
    const int row = blockIdx.x, tid = threadIdx.x;
    const int lane = tid & 63, w = tid >> 6;
    const float4 v = *(const float4*)(x + (size_t)row * HID_ + tid * 4);
    float vals[4] = {v.x, v.y, v.z, v.w};
    float s = vals[0] + vals[1] + vals[2] + vals[3];
    float ss = vals[0]*vals[0] + vals[1]*vals[1] + vals[2]*vals[2] + vals[3]*vals[3];
    for (int off = 32; off; off >>= 1) { s += __shfl_down(s, off); ss += __shfl_down(ss, off); }
    __shared__ float rs[4], rss[4], mv[2];
    if (lane == 0) { rs[w] = s; rss[w] = ss; }
    __syncthreads();
    if (tid == 0) {
        float S = rs[0] + rs[1] + rs[2] + rs[3];
        float SS = rss[0] + rss[1] + rss[2] + rss[3];
        float mean = S * (1.0f / HID_);
        float var = SS * (1.0f / HID_) - mean * mean;
        mv[0] = mean; mv[1] = rsqrtf(var + 1e-8f);
    }
    __syncthreads();
    const float mean = mv[0], rstd = mv[1];
    #pragma unroll
    for (int e = 0; e < 4; ++e) {
        int c = tid * 4 + e;
        out[(size_t)row * HID_ + c] = __float2bfloat16((vals[e] - mean) * rstd * g[c] + b[c]);
    }
}

// ---------------- bf16 MFMA GEMM, 128x128 tile, global_load_lds + 2-phase dbuf ----------------
// C[M,N] = A[M,K] * B[N,K]^T over K-range [z*kTiles*32, ...)
// EPI 0: outB = bf16(v);  EPI 2: outB = bf16(gelu(v+bias[col]));  EPI 3: outF[z*MN+o] = v
template <int EPI>
__global__ __launch_bounds__(256) void k_gemm128(const bf16* __restrict__ A,
                                                 const bf16* __restrict__ B,
                                                 bf16* __restrict__ outB,
                                                 float* __restrict__ outF,
                                                 const float* __restrict__ bias,
                                                 int N, int K, int kTiles, int MN) {
    __shared__ __align__(16) short As[2][4096];   // [128][32] swizzled
    __shared__ __align__(16) short Bs[2][4096];
    const int tid = threadIdx.x;
    const int bm = blockIdx.x * 128, bn = blockIdx.y * 128;
    const int lane = tid & 63, w = tid >> 6;
    const int wr = w >> 1, wc = w & 1;            // wave quadrant: 64 x 64
    const int k0base = blockIdx.z * kTiles * 32;

    // staging: pre-swizzled global source, linear LDS dest. 16 rows per gload.
    const int crow = lane >> 2;                   // 0..15
    const int c16p = lane & 3;
    const int coll = (c16p ^ ((crow >> 1) & 3)) * 8;   // swizzled k element offset
    const short* Ag = (const short*)A;
    const short* Bg = (const short*)B;
    const size_t a_off0 = (size_t)(bm + w * 32 + crow) * K + coll;
    const size_t a_off1 = (size_t)(bm + w * 32 + 16 + crow) * K + coll;
    const size_t b_off0 = (size_t)(bn + w * 32 + crow) * K + coll;
    const size_t b_off1 = (size_t)(bn + w * 32 + 16 + crow) * K + coll;

    auto stage = [&](int buf, int k0) {
        __builtin_amdgcn_global_load_lds((gu32*)(Ag + a_off0 + k0), (lu32*)&As[buf][w * 1024], 16, 0, 0);
        __builtin_amdgcn_global_load_lds((gu32*)(Ag + a_off1 + k0), (lu32*)&As[buf][w * 1024 + 512], 16, 0, 0);
        __builtin_amdgcn_global_load_lds((gu32*)(Bg + b_off0 + k0), (lu32*)&Bs[buf][w * 1024], 16, 0, 0);
        __builtin_amdgcn_global_load_lds((gu32*)(Bg + b_off1 + k0), (lu32*)&Bs[buf][w * 1024 + 512], 16, 0, 0);
    };

    const int fr = lane & 15, kq = lane >> 4;
    const int xbyte = ((kq ^ ((fr >> 1) & 3)) << 4);

    f32x4 acc[4][4] = {};
    stage(0, k0base);
    __syncthreads();

    for (int t = 0; t < kTiles; ++t) {
        if (t + 1 < kTiles) stage((t + 1) & 1, k0base + (t + 1) * 32);
        const char* Ab = (const char*)As[t & 1];
        const char* Bb = (const char*)Bs[t & 1];
        short8 af[4], bfv[4];
        #pragma unroll
        for (int m2 = 0; m2 < 4; ++m2)
            af[m2] = *(const short8*)(Ab + ((wr * 64 + m2 * 16 + fr) << 6) + xbyte);
        #pragma unroll
        for (int n2 = 0; n2 < 4; ++n2)
            bfv[n2] = *(const short8*)(Bb + ((wc * 64 + n2 * 16 + fr) << 6) + xbyte);
        #pragma unroll
        for (int m2 = 0; m2 < 4; ++m2)
            #pragma unroll
            for (int n2 = 0; n2 < 4; ++n2)
                acc[m2][n2] = __builtin_amdgcn_mfma_f32_16x16x32_bf16(af[m2], bfv[n2], acc[m2][n2], 0, 0, 0);
        __syncthreads();
    }

    const int cr = kq * 4, cc = fr;
    #pragma unroll
    for (int m2 = 0; m2 < 4; ++m2) {
        #pragma unroll
        for (int n2 = 0; n2 < 4; ++n2) {
            const int col = bn + wc * 64 + n2 * 16 + cc;
            #pragma unroll
            for (int e = 0; e < 4; ++e) {
                const int row = bm + wr * 64 + m2 * 16 + cr + e;
                const size_t o = (size_t)row * N + col;
                float v = acc[m2][n2][e];
                if (EPI == 0) {
                    outB[o] = __float2bfloat16(v);
                } else if (EPI == 2) {
                    float xg = v + bias[col];
                    float gl = 0.5f * xg * (1.0f + erff(xg * 0.70710678f));
                    outB[o] = __float2bfloat16(gl);
                } else {
                    outF[(size_t)blockIdx.z * MN + o] = v;
                }
            }
        }
    }
}

// ---------------- split-K reduce + bias + residual + LayerNorm (row per block) ----------------
template <int S>
__global__ __launch_bounds__(256) void k_reduce_ln(const float* __restrict__ parts,
                                                   const float* __restrict__ bias,
                                                   const float* __restrict__ res,
                                                   const float* __restrict__ g,
                                                   const float* __restrict__ b,
                                                   float* __restrict__ outH,
                                                   bf16* __restrict__ outX) {
    const int row = blockIdx.x, tid = threadIdx.x;
    const int lane = tid & 63, w = tid >> 6;
    const int idx = row * 256 + tid;
    const float4* p = (const float4*)parts;
    float4 s = p[idx];
    #pragma unroll
    for (int ss = 1; ss < S; ++ss) {
        float4 t2 = p[idx + (size_t)ss * 524288];
        s.x += t2.x; s.y += t2.y; s.z += t2.z; s.w += t2.w;
    }
    float4 bb = ((const float4*)bias)[tid];
    float4 rr = ((const float4*)res)[idx];
    float vals[4] = {s.x + bb.x + rr.x, s.y + bb.y + rr.y, s.z + bb.z + rr.z, s.w + bb.w + rr.w};
    ((float4*)outH)[idx] = (float4){vals[0], vals[1], vals[2], vals[3]};

    float sum = vals[0] + vals[1] + vals[2] + vals[3];
    float ssq = vals[0]*vals[0] + vals[1]*vals[1] + vals[2]*vals[2] + vals[3]*vals[3];
    for (int off = 32; off; off >>= 1) { sum += __shfl_down(sum, off); ssq += __shfl_down(ssq, off); }
    __shared__ float rs[4], rss[4], mv[2];
    if (lane == 0) { rs[w] = sum; rss[w] = ssq; }
    __syncthreads();
    if (tid == 0) {
        float S2 = rs[0] + rs[1] + rs[2] + rs[3];
        float SS = rss[0] + rss[1] + rss[2] + rss[3];
        float mean = S2 * (1.0f / HID_);
        float var = SS * (1.0f / HID_) - mean * mean;
        mv[0] = mean; mv[1] = rsqrtf(var + 1e-8f);
    }
    __syncthreads();
    const float mean = mv[0], rstd = mv[1];
    #pragma unroll
    for (int e = 0; e < 4; ++e) {
        int c = tid * 4 + e;
        outX[(size_t)row * HID_ + c] = __float2bfloat16((vals[e] - mean) * rstd * g[c] + b[c]);
    }
}

// ---------------- split-K reduce + bias + residual (elementwise, fp32 out) ----------------
template <int S>
__global__ __launch_bounds__(256) void k_reduce(const float* __restrict__ parts,
                                                const float* __restrict__ bias,
                                                const float* __restrict__ res,
                                                float* __restrict__ out) {
    const int idx = blockIdx.x * 256 + threadIdx.x;
    const float4* p = (const float4*)parts;
    float4 s = p[idx];
    #pragma unroll
    for (int ss = 1; ss < S; ++ss) {
        float4 t2 = p[idx + (size_t)ss * 524288];
        s.x += t2.x; s.y += t2.y; s.z += t2.z; s.w += t2.w;
    }
    float4 bb = ((const float4*)bias)[idx & 255];
    float4 rr = ((const float4*)res)[idx];
    float4 o = {s.x + bb.x + rr.x, s.y + bb.y + rr.y, s.z + bb.z + rr.z, s.w + bb.w + rr.w};
    ((float4*)out)[idx] = o;
}

// ---------------- relpos -> band-aligned transposed bias tables ----------------
// MODE 0 (c2p from Q): c2p[i][p] -> BT[h][bq][t=p+il][il]  (coalesced via LDS re-tile)
// MODE 1 (p2c from K): p2c[j][u] -> BT[h][bq][t=j-64bq+128][il=(j+u-128)&63]
template <int MODE>
__global__ __launch_bounds__(256) void k_relpos_bt(const bf16* __restrict__ X,
                                                   const bf16* __restrict__ Pt,
                                                   bf16* __restrict__ bt) {
    const int bq = blockIdx.x, h = blockIdx.y;
    const int r0 = bq * 64;
    const int tid = threadIdx.x, lane = tid & 63, w = tid >> 6;
    const int fr = lane & 15, kg = (lane >> 4) << 3;
    const int cr = (lane >> 4) << 2, cc = lane & 15;

    short8 af[2];
    #pragma unroll
    for (int ks = 0; ks < 2; ++ks)
        af[ks] = *(const short8*)&X[(size_t)(r0 + w * 16 + fr) * QKVS + h * HD + ks * 32 + kg];

    f32x4 acc[20];
    #pragma unroll
    for (int fj = 0; fj < 20; ++fj) acc[fj] = (f32x4){0.f, 0.f, 0.f, 0.f};

    #pragma unroll
    for (int fj = 0; fj < 20; ++fj) {
        int p = fj * 16 + fr;
        int pc = p < NPOS ? p : (NPOS - 1);
        #pragma unroll
        for (int ks = 0; ks < 2; ++ks) {
            short8 bp = *(const short8*)&Pt[((size_t)h * NPOS + pc) * HD + ks * 32 + kg];
            acc[fj] = __builtin_amdgcn_mfma_f32_16x16x32_bf16(af[ks], bp, acc[fj], 0, 0, 0);
        }
    }

    if (MODE == 0) {
        __shared__ short ld[64][328];
        #pragma unroll
        for (int fj = 0; fj < 20; ++fj) {
            int p = fj * 16 + cc;
            if (p < NPOS) {
                #pragma unroll
                for (int e = 0; e < 4; ++e)
                    ld[w * 16 + cr + e][p] = f2bs(acc[fj][e]);
            }
        }
        __syncthreads();
        short* outp = (short*)bt + (size_t)(h * NTILE + bq) * BT_TILE;
        #pragma unroll
        for (int i = 0; i < 10; ++i) {
            int idx8 = (tid + i * 256) * 8;
            int t = idx8 >> 6, il0 = idx8 & 63;
            short8 v;
            #pragma unroll
            for (int e = 0; e < 8; ++e) {
                int il = il0 + e, p = t - il;
                v[e] = (p >= 0 && p < NPOS) ? ld[il][p] : (short)0;
            }
            *(short8*)(outp + t * 64 + il0) = v;
        }
    } else {
        #pragma unroll
        for (int fj = 0; fj < 20; ++fj) {
            int p = fj * 16 + cc;
            if (p < NPOS) {
                #pragma unroll
                for (int e = 0; e < 4; ++e) {
                    int rloc = w * 16 + cr + e;
                    int j = r0 + rloc;
                    int s = j + p - 128;
                    if (s >= 0 && s < L_SEQ) {
                        int tb = s >> 6, il = s & 63;
                        int t = j - tb * 64 + 128;
                        bt[((size_t)(h * NTILE + tb) * 320 + t) * 64 + il] =
                            __float2bfloat16(acc[fj][e]);
                    }
                }
            }
        }
    }
}

// ---------------- MFMA banded attention (bias via identity-MFMA) ----------------
__global__ __launch_bounds__(256, 3) void k_attn_mfma(const bf16* __restrict__ qb,
                                                      const bf16* __restrict__ kb,
                                                      const bf16* __restrict__ vb,
                                                      const bf16* __restrict__ bt1,
                                                      const bf16* __restrict__ bt2,
                                                      bf16* __restrict__ ctxb) {
    const int bq = blockIdx.x, h = blockIdx.y;
    const int qi0 = bq * 64, j0 = qi0 - WHALF;
    const int tid = threadIdx.x, lane = tid & 63, w = tid >> 6;
    const int fr = lane & 15, kq = lane >> 4, kg = kq << 3;
    const int cr = kq << 2, cc = fr;

    __shared__ short KVs[20480];            // K: [320][64] swizzled; then Vt: [64][320] swizzled
    __shared__ __align__(16) short Ps[64][72];
    char* KVb = (char*)KVs;

    #pragma unroll
    for (int p = 0; p < 10; ++p) {
        int c = tid + p * 256;
        int t = c >> 3, d8 = (c & 7) << 3;
        int j = j0 + t;
        short8 v = {};
        if (j >= 0 && j < L_SEQ) v = *(const short8*)&kb[(size_t)j * QKVS + h * HD + d8];
        int byte = (t * 128 + d8 * 2) ^ ((t & 7) << 4);
        *(short8*)(KVb + byte) = v;
    }
    short8 aq[2];
    #pragma unroll
    for (int ks = 0; ks < 2; ++ks)
        aq[ks] = *(const short8*)&qb[(size_t)(qi0 + w * 16 + fr) * QKVS + h * HD + ks * 32 + kg];

    short8 ifrag = {};
    {
        int d = fr - kg;
        if (d >= 0 && d < 8) ifrag[d] = (short)0x3F80;
    }
    __syncthreads();

    f32x4 acc[20];
    #pragma unroll
    for (int fj = 0; fj < 20; ++fj) acc[fj] = (f32x4){0.f, 0.f, 0.f, 0.f};
    #pragma unroll
    for (int ks = 0; ks < 2; ++ks) {
        #pragma unroll
        for (int fj = 0; fj < 20; ++fj) {
            int t = fj * 16 + fr;
            int byte = (t * 128 + (ks * 32 + kg) * 2) ^ ((t & 7) << 4);
            short8 bk = *(const short8*)(KVb + byte);
            acc[fj] = __builtin_amdgcn_mfma_f32_16x16x32_bf16(aq[ks], bk, acc[fj], 0, 0, 0);
        }
    }
    __syncthreads();

    short8 vreg[10];
    #pragma unroll
    for (int p = 0; p < 10; ++p) {
        int c = tid + p * 256;
        int t = c >> 3, d8 = (c & 7) << 3;
        int j = j0 + t;
        short8 v = {};
        if (j >= 0 && j < L_SEQ) v = *(const short8*)&vb[(size_t)j * QKVS + h * HD + d8];
        vreg[p] = v;
    }

    {
        const short* t1 = (const short*)bt1 + (size_t)(h * NTILE + bq) * BT_TILE;
        const short* t2 = (const short*)bt2 + (size_t)(h * NTILE + bq) * BT_TILE;
        #pragma unroll
        for (int fj = 0; fj < 20; ++fj) {
            int off = (fj * 16 + fr) * 64 + w * 16 + kg;
            short8 b1 = *(const short8*)(t1 + off);
            short8 b2 = *(const short8*)(t2 + off);
            acc[fj] = __builtin_amdgcn_mfma_f32_16x16x32_bf16(ifrag, b1, acc[fj], 0, 0, 0);
            acc[fj] = __builtin_amdgcn_mfma_f32_16x16x32_bf16(ifrag, b2, acc[fj], 0, 0, 0);
        }
    }

    const int qrel0 = w * 16 + cr;
    #pragma unroll
    for (int fj = 0; fj < 20; ++fj) {
        int t = fj * 16 + cc;
        int j = j0 + t;
        #pragma unroll
        for (int e = 0; e < 4; ++e) {
            int qr = qrel0 + e;
            bool valid = (j >= 0) && (j < L_SEQ) && (t >= qr) && (t <= qr + 256);
            acc[fj][e] = valid ? acc[fj][e] : -3.0e38f;
        }
    }

    float mx[4], sm[4];
    #pragma unroll
    for (int e = 0; e < 4; ++e) {
        float m = acc[0][e];
        #pragma unroll
        for (int fj = 1; fj < 20; ++fj) m = fmaxf(m, acc[fj][e]);
        mx[e] = m;
    }
    #pragma unroll
    for (int msk = 1; msk < 16; msk <<= 1)
        #pragma unroll
        for (int e = 0; e < 4; ++e) mx[e] = fmaxf(mx[e], __shfl_xor(mx[e], msk));
    #pragma unroll
    for (int e = 0; e < 4; ++e) sm[e] = 0.f;
    #pragma unroll
    for (int fj = 0; fj < 20; ++fj)
        #pragma unroll
        for (int e = 0; e < 4; ++e) {
            float p = __expf(acc[fj][e] - mx[e]);
            acc[fj][e] = p;
            sm[e] += p;
        }
    #pragma unroll
    for (int msk = 1; msk < 16; msk <<= 1)
        #pragma unroll
        for (int e = 0; e < 4; ++e) sm[e] += __shfl_xor(sm[e], msk);
    float rinv[4];
    #pragma unroll
    for (int e = 0; e < 4; ++e) rinv[e] = 1.0f / sm[e];

    #pragma unroll
    for (int p = 0; p < 10; ++p) {
        int c = tid + p * 256;
        int t = c >> 3, d8 = (c & 7) << 3;
        #pragma unroll
        for (int e = 0; e < 8; ++e) {
            int d = d8 + e;
            int byte = (d * 640 + t * 2) ^ ((d & 7) << 4);
            *(short*)(KVb + byte) = vreg[p][e];
        }
    }

    f32x4 acc2[4];
    #pragma unroll
    for (int f = 0; f < 4; ++f) acc2[f] = (f32x4){0.f, 0.f, 0.f, 0.f};
    #pragma unroll
    for (int ch = 0; ch < 5; ++ch) {
        #pragma unroll
        for (int fjl = 0; fjl < 4; ++fjl) {
            int fj = ch * 4 + fjl;
            int col = fjl * 16 + cc;
            #pragma unroll
            for (int e = 0; e < 4; ++e)
                Ps[w * 16 + cr + e][col] = f2bs(acc[fj][e]);
        }
        if (ch == 0) __syncthreads();
        #pragma unroll
        for (int ks2 = 0; ks2 < 2; ++ks2) {
            short8 pa = *(const short8*)&Ps[w * 16 + fr][ks2 * 32 + kg];
            #pragma unroll
            for (int f = 0; f < 4; ++f) {
                int d = f * 16 + fr;
                int tg = ch * 64 + ks2 * 32 + kg;
                int byte = (d * 640 + tg * 2) ^ ((d & 7) << 4);
                short8 bv = *(const short8*)(KVb + byte);
                acc2[f] = __builtin_amdgcn_mfma_f32_16x16x32_bf16(pa, bv, acc2[f], 0, 0, 0);
            }
        }
    }

    #pragma unroll
    for (int f = 0; f < 4; ++f)
        #pragma unroll
        for (int e = 0; e < 4; ++e) {
            int row = qi0 + w * 16 + cr + e;
            int d = f * 16 + cc;
            ctxb[(size_t)row * HID_ + h * HD + d] = __float2bfloat16(acc2[f][e] * rinv[e]);
        }
}

// ---------------- launch ----------------
extern "C" void kernel_launch(void* const* d_in, const int* in_sizes, int n_in,
                              void* d_out, int out_size, void* d_ws, size_t ws_size,
                              hipStream_t stream) {
    const float* hid  = (const float*)d_in[0];
    const float* wq   = (const float*)d_in[2];
    const float* wk   = (const float*)d_in[3];
    const float* wv   = (const float*)d_in[4];
    const float* pk   = (const float*)d_in[5];
    const float* pq   = (const float*)d_in[6];
    const float* wo   = (const float*)d_in[7];
    const float* bo   = (const float*)d_in[8];
    const float* ln1g = (const float*)d_in[9];
    const float* ln1b = (const float*)d_in[10];
    const float* ln2g = (const float*)d_in[11];
    const float* ln2b = (const float*)d_in[12];
    const float* w1   = (const float*)d_in[13];
    const float* b1   = (const float*)d_in[14];
    const float* w2   = (const float*)d_in[15];
    const float* b2   = (const float*)d_in[16];
    float* out = (float*)d_out;

    char* ws = (char*)d_ws;
    size_t off = 0;
    auto alloc = [&](size_t bytes) -> void* {
        void* p = ws + off;
        off += (bytes + 255) & ~(size_t)255;
        return p;
    };
    const size_t BT_BYTES = (size_t)NH * NTILE * BT_TILE * 2 + 256;
    bf16* wqkvb = (bf16*)alloc((size_t)QKVS * HID_ * 2);
    bf16* wob   = (bf16*)alloc((size_t)HID_ * HID_ * 2);
    bf16* w1b   = (bf16*)alloc((size_t)HID_ * FF_ * 2);
    bf16* w2b   = (bf16*)alloc((size_t)HID_ * FF_ * 2);
    bf16* pkt   = (bf16*)alloc((size_t)NH * NPOS * HD * 2);
    bf16* pqt   = (bf16*)alloc((size_t)NH * NPOS * HD * 2);
    bf16* x1b   = (bf16*)alloc((size_t)L_SEQ * HID_ * 2);
    bf16* qkv   = (bf16*)alloc((size_t)L_SEQ * QKVS * 2);
    bf16* bt1   = (bf16*)alloc(BT_BYTES);
    bf16* bt2   = (bf16*)alloc(BT_BYTES);
    bf16* ctxb  = (bf16*)alloc((size_t)L_SEQ * HID_ * 2);
    float* hbuf = (float*)alloc((size_t)L_SEQ * HID_ * 4);
    bf16* x2b   = (bf16*)alloc((size_t)L_SEQ * HID_ * 2);
    bf16* ffb   = (bf16*)alloc((size_t)L_SEQ * FF_ * 2);
    (void)ws_size; (void)in_sizes; (void)n_in; (void)out_size;

    float* wopart  = (float*)ffb;   // dead before FF1 writes ffb
    float* ff2part = (float*)qkv;   // spans qkv+bt1, both dead after attn

    // weight + pos conversions (merged)
    k_wt_all<<<3072, 256, 0, stream>>>(wq, wk, wv, wo, w1, w2, wqkvb, wob, w1b, w2b);
    k_pos2<<<2056, 256, 0, stream>>>(pk, pq, pkt, pqt);

    // LN1
    k_layernorm<<<L_SEQ, 256, 0, stream>>>(hid, ln1g, ln1b, x1b);

    const int MN = L_SEQ * HID_;
    // fused QKV projection
    k_gemm128<0><<<dim3(16, 24, 1), 256, 0, stream>>>(x1b, wqkvb, qkv, nullptr, nullptr, QKVS, HID_, 32, MN);

    // band-aligned bias tables
    dim3 g_rp(NTILE, NH);
    k_relpos_bt<0><<<g_rp, 256, 0, stream>>>(qkv, pkt, bt1);
    k_relpos_bt<1><<<g_rp, 256, 0, stream>>>(qkv + 1024, pqt, bt2);

    // banded attention
    k_attn_mfma<<<dim3(NTILE, NH), 256, 0, stream>>>(qkv, qkv + 1024, qkv + 2048, bt1, bt2, ctxb);

    // Wo (split-K=2) + fused reduce(bias+residual)+LN2 -> hbuf, x2b
    k_gemm128<3><<<dim3(16, 8, 2), 256, 0, stream>>>(ctxb, wob, nullptr, wopart, nullptr, HID_, HID_, 16, MN);
    k_reduce_ln<2><<<L_SEQ, 256, 0, stream>>>(wopart, bo, hid, ln2g, ln2b, hbuf, x2b);

    // FF1: gelu(x2 @ w1 + b1) -> ffb
    k_gemm128<2><<<dim3(16, 32, 1), 256, 0, stream>>>(x2b, w1b, ffb, nullptr, b1, FF_, HID_, 32, MN);

    // FF2 (split-K=4) + reduce(bias+residual) -> out
    k_gemm128<3><<<dim3(16, 8, 4), 256, 0, stream>>>(ffb, w2b, nullptr, ff2part, nullptr, HID_, FF_, 32, MN);
    k_reduce<4><<<2048, 256, 0, stream>>>(ff2part, b2, hbuf, out);
}

// Round 8
// 311.526 us; speedup vs baseline: 3.3443x; 1.0498x over previous
//
#include <hip/hip_runtime.h>
#include <hip/hip_bf16.h>
#include <cstdint>

typedef __hip_bfloat16 bf16;
typedef __attribute__((ext_vector_type(8))) short short8;
typedef __attribute__((ext_vector_type(4))) float f32x4;
typedef __attribute__((address_space(1))) const unsigned int gu32;
typedef __attribute__((address_space(3))) unsigned int lu32;

#define L_SEQ 2048
#define HID_  1024
#define NH    16
#define HD    64
#define FF_   4096
#define NPOS  257   // 2W+1
#define WHALF 128
#define QKVS  3072  // fused qkv row stride
#define NTILE 32    // L_SEQ/64
#define BT_TILE (320 * 64)   // shorts per (h,tile) bias tile

__device__ inline short f2bs(float f) {
    bf16 b = __float2bfloat16(f);
    return *reinterpret_cast<short*>(&b);
}

// ---------------- merged weight transpose-convert: 6 weights, fp32 [K][N] -> bf16 [N][K] ----
__global__ __launch_bounds__(256) void k_wt_all(const float* __restrict__ wq,
                                                const float* __restrict__ wk,
                                                const float* __restrict__ wv,
                                                const float* __restrict__ wo,
                                                const float* __restrict__ w1,
                                                const float* __restrict__ w2,
                                                bf16* __restrict__ wqkvb,
                                                bf16* __restrict__ wob,
                                                bf16* __restrict__ w1b,
                                                bf16* __restrict__ w2b) {
    const int id = blockIdx.x;
    const float* src; bf16* dst; int K, N, tile;
    if (id < 768)       { int s = id >> 8; tile = id & 255;
                          src = s == 0 ? wq : (s == 1 ? wk : wv);
                          dst = wqkvb + (size_t)s * 1024 * 1024; K = 1024; N = 1024; }
    else if (id < 1024) { tile = id - 768;  src = wo; dst = wob; K = 1024; N = 1024; }
    else if (id < 2048) { tile = id - 1024; src = w1; dst = w1b; K = 1024; N = 4096; }
    else                { tile = id - 2048; src = w2; dst = w2b; K = 4096; N = 1024; }
    const int ktiles = K >> 6;
    const int k0 = (tile % ktiles) * 64, n0 = (tile / ktiles) * 64;

    __shared__ float t[64][65];
    const int c = threadIdx.x & 63, r4 = threadIdx.x >> 6;
    #pragma unroll
    for (int i = 0; i < 16; ++i)
        t[i * 4 + r4][c] = src[(size_t)(k0 + i * 4 + r4) * N + n0 + c];
    __syncthreads();
    #pragma unroll
    for (int i = 0; i < 16; ++i) {
        int n = i * 4 + r4;
        dst[(size_t)(n0 + n) * K + k0 + c] = __float2bfloat16(t[c][n]);
    }
}

// pos [H][64][257] fp32 -> Pt [H][257][64] bf16, both tables in one launch
__global__ void k_pos2(const float* __restrict__ pk, const float* __restrict__ pq,
                       bf16* __restrict__ pkt, bf16* __restrict__ pqt) {
    const int T = NH * NPOS * HD;
    for (int gi = blockIdx.x * blockDim.x + threadIdx.x; gi < 2 * T;
         gi += gridDim.x * blockDim.x) {
        const float* src = gi < T ? pk : pq;
        bf16* dst = gi < T ? pkt : pqt;
        int idx = gi < T ? gi : gi - T;
        int d = idx & 63;
        int r = idx >> 6;
        int t = r % NPOS;
        int h = r / NPOS;
        dst[idx] = __float2bfloat16(src[((size_t)h * HD + d) * NPOS + t]);
    }
}

// ---------------- layernorm ----------------
__global__ __launch_bounds__(256) void k_layernorm(const float* __restrict__ x,
                                                   const float* __restrict__ g,
                                                   const float* __restrict__ b,
                                                   bf16* __restrict__ out) {
    const int row = blockIdx.x, tid = threadIdx.x;
    const int lane = tid & 63, w = tid >> 6;
    const float4 v = *(const float4*)(x + (size_t)row * HID_ + tid * 4);
    float vals[4] = {v.x, v.y, v.z, v.w};
    float s = vals[0] + vals[1] + vals[2] + vals[3];
    float ss = vals[0]*vals[0] + vals[1]*vals[1] + vals[2]*vals[2] + vals[3]*vals[3];
    for (int off = 32; off; off >>= 1) { s += __shfl_down(s, off); ss += __shfl_down(ss, off); }
    __shared__ float rs[4], rss[4], mv[2];
    if (lane == 0) { rs[w] = s; rss[w] = ss; }
    __syncthreads();
    if (tid == 0) {
        float S = rs[0] + rs[1] + rs[2] + rs[3];
        float SS = rss[0] + rss[1] + rss[2] + rss[3];
        float mean = S * (1.0f / HID_);
        float var = SS * (1.0f / HID_) - mean * mean;
        mv[0] = mean; mv[1] = rsqrtf(var + 1e-8f);
    }
    __syncthreads();
    const float mean = mv[0], rstd = mv[1];
    #pragma unroll
    for (int e = 0; e < 4; ++e) {
        int c = tid * 4 + e;
        out[(size_t)row * HID_ + c] = __float2bfloat16((vals[e] - mean) * rstd * g[c] + b[c]);
    }
}

// ---------------- bf16 MFMA GEMM, 64x128 tile, global_load_lds + 2-phase dbuf ----------------
// C[M,N] = A[M,K] * B[N,K]^T over K-range [z*kTiles*32, ...)
// EPI 0: outB = bf16(v);  EPI 2: outB = bf16(gelu(v+bias[col]));  EPI 3: outF[z*MN+o] = v
template <int EPI>
__global__ __launch_bounds__(256) void k_gemm64(const bf16* __restrict__ A,
                                                const bf16* __restrict__ B,
                                                bf16* __restrict__ outB,
                                                float* __restrict__ outF,
                                                const float* __restrict__ bias,
                                                int N, int K, int kTiles, int MN) {
    __shared__ __align__(16) short As[2][2048];   // [64][32] swizzled
    __shared__ __align__(16) short Bs[2][4096];   // [128][32] swizzled
    const int tid = threadIdx.x;
    const int bm = blockIdx.x * 64, bn = blockIdx.y * 128;
    const int lane = tid & 63, w = tid >> 6;
    const int wr = w >> 1, wc = w & 1;            // wave tile: 32 x 64
    const int k0base = blockIdx.z * kTiles * 32;

    // staging: pre-swizzled global source, linear LDS dest (16 rows per gload)
    const int crow = lane >> 2;                   // 0..15
    const int c16p = lane & 3;
    const int coll = (c16p ^ ((crow >> 1) & 3)) * 8;   // swizzled k element offset
    const short* Ag = (const short*)A;
    const short* Bg = (const short*)B;
    const size_t a_off  = (size_t)(bm + w * 16 + crow) * K + coll;
    const size_t b_off0 = (size_t)(bn + w * 32 + crow) * K + coll;
    const size_t b_off1 = (size_t)(bn + w * 32 + 16 + crow) * K + coll;

    auto stage = [&](int buf, int k0) {
        __builtin_amdgcn_global_load_lds((gu32*)(Ag + a_off + k0), (lu32*)&As[buf][w * 512], 16, 0, 0);
        __builtin_amdgcn_global_load_lds((gu32*)(Bg + b_off0 + k0), (lu32*)&Bs[buf][w * 1024], 16, 0, 0);
        __builtin_amdgcn_global_load_lds((gu32*)(Bg + b_off1 + k0), (lu32*)&Bs[buf][w * 1024 + 512], 16, 0, 0);
    };

    // fragment read geometry (swizzled, conflict-free: fr0-7 -> 8 distinct banks, 2-way alias free)
    const int fr = lane & 15, kq = lane >> 4;
    const int xbyte = ((kq ^ ((fr >> 1) & 3)) << 4);

    f32x4 acc[2][4] = {};
    stage(0, k0base);
    __syncthreads();

    for (int t = 0; t < kTiles; ++t) {
        if (t + 1 < kTiles) stage((t + 1) & 1, k0base + (t + 1) * 32);
        const char* Ab = (const char*)As[t & 1];
        const char* Bb = (const char*)Bs[t & 1];
        short8 af[2], bfv[4];
        #pragma unroll
        for (int m2 = 0; m2 < 2; ++m2)
            af[m2] = *(const short8*)(Ab + ((wr * 32 + m2 * 16 + fr) << 6) + xbyte);
        #pragma unroll
        for (int n2 = 0; n2 < 4; ++n2)
            bfv[n2] = *(const short8*)(Bb + ((wc * 64 + n2 * 16 + fr) << 6) + xbyte);
        #pragma unroll
        for (int m2 = 0; m2 < 2; ++m2)
            #pragma unroll
            for (int n2 = 0; n2 < 4; ++n2)
                acc[m2][n2] = __builtin_amdgcn_mfma_f32_16x16x32_bf16(af[m2], bfv[n2], acc[m2][n2], 0, 0, 0);
        __syncthreads();
    }

    const int cr = kq * 4, cc = fr;
    #pragma unroll
    for (int m2 = 0; m2 < 2; ++m2) {
        #pragma unroll
        for (int n2 = 0; n2 < 4; ++n2) {
            const int col = bn + wc * 64 + n2 * 16 + cc;
            #pragma unroll
            for (int e = 0; e < 4; ++e) {
                const int row = bm + wr * 32 + m2 * 16 + cr + e;
                const size_t o = (size_t)row * N + col;
                float v = acc[m2][n2][e];
                if (EPI == 0) {
                    outB[o] = __float2bfloat16(v);
                } else if (EPI == 2) {
                    float xg = v + bias[col];
                    float gl = 0.5f * xg * (1.0f + erff(xg * 0.70710678f));
                    outB[o] = __float2bfloat16(gl);
                } else {
                    outF[(size_t)blockIdx.z * MN + o] = v;
                }
            }
        }
    }
}

// ---------------- split-K reduce + bias + residual + LayerNorm (row per block) ----------------
template <int S>
__global__ __launch_bounds__(256) void k_reduce_ln(const float* __restrict__ parts,
                                                   const float* __restrict__ bias,
                                                   const float* __restrict__ res,
                                                   const float* __restrict__ g,
                                                   const float* __restrict__ b,
                                                   float* __restrict__ outH,
                                                   bf16* __restrict__ outX) {
    const int row = blockIdx.x, tid = threadIdx.x;
    const int lane = tid & 63, w = tid >> 6;
    const int idx = row * 256 + tid;
    const float4* p = (const float4*)parts;
    float4 s = p[idx];
    #pragma unroll
    for (int ss = 1; ss < S; ++ss) {
        float4 t2 = p[idx + (size_t)ss * 524288];
        s.x += t2.x; s.y += t2.y; s.z += t2.z; s.w += t2.w;
    }
    float4 bb = ((const float4*)bias)[tid];
    float4 rr = ((const float4*)res)[idx];
    float vals[4] = {s.x + bb.x + rr.x, s.y + bb.y + rr.y, s.z + bb.z + rr.z, s.w + bb.w + rr.w};
    ((float4*)outH)[idx] = (float4){vals[0], vals[1], vals[2], vals[3]};

    float sum = vals[0] + vals[1] + vals[2] + vals[3];
    float ssq = vals[0]*vals[0] + vals[1]*vals[1] + vals[2]*vals[2] + vals[3]*vals[3];
    for (int off = 32; off; off >>= 1) { sum += __shfl_down(sum, off); ssq += __shfl_down(ssq, off); }
    __shared__ float rs[4], rss[4], mv[2];
    if (lane == 0) { rs[w] = sum; rss[w] = ssq; }
    __syncthreads();
    if (tid == 0) {
        float S2 = rs[0] + rs[1] + rs[2] + rs[3];
        float SS = rss[0] + rss[1] + rss[2] + rss[3];
        float mean = S2 * (1.0f / HID_);
        float var = SS * (1.0f / HID_) - mean * mean;
        mv[0] = mean; mv[1] = rsqrtf(var + 1e-8f);
    }
    __syncthreads();
    const float mean = mv[0], rstd = mv[1];
    #pragma unroll
    for (int e = 0; e < 4; ++e) {
        int c = tid * 4 + e;
        outX[(size_t)row * HID_ + c] = __float2bfloat16((vals[e] - mean) * rstd * g[c] + b[c]);
    }
}

// ---------------- split-K reduce + bias + residual (elementwise, fp32 out) ----------------
template <int S>
__global__ __launch_bounds__(256) void k_reduce(const float* __restrict__ parts,
                                                const float* __restrict__ bias,
                                                const float* __restrict__ res,
                                                float* __restrict__ out) {
    const int idx = blockIdx.x * 256 + threadIdx.x;
    const float4* p = (const float4*)parts;
    float4 s = p[idx];
    #pragma unroll
    for (int ss = 1; ss < S; ++ss) {
        float4 t2 = p[idx + (size_t)ss * 524288];
        s.x += t2.x; s.y += t2.y; s.z += t2.z; s.w += t2.w;
    }
    float4 bb = ((const float4*)bias)[idx & 255];
    float4 rr = ((const float4*)res)[idx];
    float4 o = {s.x + bb.x + rr.x, s.y + bb.y + rr.y, s.z + bb.z + rr.z, s.w + bb.w + rr.w};
    ((float4*)out)[idx] = o;
}

// ---------------- relpos -> band-aligned transposed bias tables ----------------
// MODE 0 (c2p from Q): c2p[i][p] -> BT[h][bq][t=p+il][il]  (coalesced via LDS re-tile)
// MODE 1 (p2c from K): p2c[j][u] -> BT[h][bq][t=j-64bq+128][il=(j+u-128)&63]
template <int MODE>
__global__ __launch_bounds__(256) void k_relpos_bt(const bf16* __restrict__ X,
                                                   const bf16* __restrict__ Pt,
                                                   bf16* __restrict__ bt) {
    const int bq = blockIdx.x, h = blockIdx.y;
    const int r0 = bq * 64;
    const int tid = threadIdx.x, lane = tid & 63, w = tid >> 6;
    const int fr = lane & 15, kg = (lane >> 4) << 3;
    const int cr = (lane >> 4) << 2, cc = lane & 15;

    short8 af[2];
    #pragma unroll
    for (int ks = 0; ks < 2; ++ks)
        af[ks] = *(const short8*)&X[(size_t)(r0 + w * 16 + fr) * QKVS + h * HD + ks * 32 + kg];

    f32x4 acc[20];
    #pragma unroll
    for (int fj = 0; fj < 20; ++fj) acc[fj] = (f32x4){0.f, 0.f, 0.f, 0.f};

    #pragma unroll
    for (int fj = 0; fj < 20; ++fj) {
        int p = fj * 16 + fr;
        int pc = p < NPOS ? p : (NPOS - 1);
        #pragma unroll
        for (int ks = 0; ks < 2; ++ks) {
            short8 bp = *(const short8*)&Pt[((size_t)h * NPOS + pc) * HD + ks * 32 + kg];
            acc[fj] = __builtin_amdgcn_mfma_f32_16x16x32_bf16(af[ks], bp, acc[fj], 0, 0, 0);
        }
    }

    if (MODE == 0) {
        __shared__ short ld[64][328];
        #pragma unroll
        for (int fj = 0; fj < 20; ++fj) {
            int p = fj * 16 + cc;
            if (p < NPOS) {
                #pragma unroll
                for (int e = 0; e < 4; ++e)
                    ld[w * 16 + cr + e][p] = f2bs(acc[fj][e]);
            }
        }
        __syncthreads();
        short* outp = (short*)bt + (size_t)(h * NTILE + bq) * BT_TILE;
        #pragma unroll
        for (int i = 0; i < 10; ++i) {
            int idx8 = (tid + i * 256) * 8;
            int t = idx8 >> 6, il0 = idx8 & 63;
            short8 v;
            #pragma unroll
            for (int e = 0; e < 8; ++e) {
                int il = il0 + e, p = t - il;
                v[e] = (p >= 0 && p < NPOS) ? ld[il][p] : (short)0;
            }
            *(short8*)(outp + t * 64 + il0) = v;
        }
    } else {
        #pragma unroll
        for (int fj = 0; fj < 20; ++fj) {
            int p = fj * 16 + cc;
            if (p < NPOS) {
                #pragma unroll
                for (int e = 0; e < 4; ++e) {
                    int rloc = w * 16 + cr + e;
                    int j = r0 + rloc;
                    int s = j + p - 128;
                    if (s >= 0 && s < L_SEQ) {
                        int tb = s >> 6, il = s & 63;
                        int t = j - tb * 64 + 128;
                        bt[((size_t)(h * NTILE + tb) * 320 + t) * 64 + il] =
                            __float2bfloat16(acc[fj][e]);
                    }
                }
            }
        }
    }
}

// ---------------- MFMA banded attention (bias via identity-MFMA) ----------------
__global__ __launch_bounds__(256, 3) void k_attn_mfma(const bf16* __restrict__ qb,
                                                      const bf16* __restrict__ kb,
                                                      const bf16* __restrict__ vb,
                                                      const bf16* __restrict__ bt1,
                                                      const bf16* __restrict__ bt2,
                                                      bf16* __restrict__ ctxb) {
    const int bq = blockIdx.x, h = blockIdx.y;
    const int qi0 = bq * 64, j0 = qi0 - WHALF;
    const int tid = threadIdx.x, lane = tid & 63, w = tid >> 6;
    const int fr = lane & 15, kq = lane >> 4, kg = kq << 3;
    const int cr = kq << 2, cc = fr;

    __shared__ short KVs[20480];            // K: [320][64] swizzled; then Vt: [64][320] swizzled
    __shared__ __align__(16) short Ps[64][72];
    char* KVb = (char*)KVs;

    #pragma unroll
    for (int p = 0; p < 10; ++p) {
        int c = tid + p * 256;
        int t = c >> 3, d8 = (c & 7) << 3;
        int j = j0 + t;
        short8 v = {};
        if (j >= 0 && j < L_SEQ) v = *(const short8*)&kb[(size_t)j * QKVS + h * HD + d8];
        int byte = (t * 128 + d8 * 2) ^ ((t & 7) << 4);
        *(short8*)(KVb + byte) = v;
    }
    short8 aq[2];
    #pragma unroll
    for (int ks = 0; ks < 2; ++ks)
        aq[ks] = *(const short8*)&qb[(size_t)(qi0 + w * 16 + fr) * QKVS + h * HD + ks * 32 + kg];

    short8 ifrag = {};
    {
        int d = fr - kg;
        if (d >= 0 && d < 8) ifrag[d] = (short)0x3F80;
    }
    __syncthreads();

    f32x4 acc[20];
    #pragma unroll
    for (int fj = 0; fj < 20; ++fj) acc[fj] = (f32x4){0.f, 0.f, 0.f, 0.f};
    #pragma unroll
    for (int ks = 0; ks < 2; ++ks) {
        #pragma unroll
        for (int fj = 0; fj < 20; ++fj) {
            int t = fj * 16 + fr;
            int byte = (t * 128 + (ks * 32 + kg) * 2) ^ ((t & 7) << 4);
            short8 bk = *(const short8*)(KVb + byte);
            acc[fj] = __builtin_amdgcn_mfma_f32_16x16x32_bf16(aq[ks], bk, acc[fj], 0, 0, 0);
        }
    }
    __syncthreads();

    short8 vreg[10];
    #pragma unroll
    for (int p = 0; p < 10; ++p) {
        int c = tid + p * 256;
        int t = c >> 3, d8 = (c & 7) << 3;
        int j = j0 + t;
        short8 v = {};
        if (j >= 0 && j < L_SEQ) v = *(const short8*)&vb[(size_t)j * QKVS + h * HD + d8];
        vreg[p] = v;
    }

    {
        const short* t1 = (const short*)bt1 + (size_t)(h * NTILE + bq) * BT_TILE;
        const short* t2 = (const short*)bt2 + (size_t)(h * NTILE + bq) * BT_TILE;
        #pragma unroll
        for (int fj = 0; fj < 20; ++fj) {
            int off = (fj * 16 + fr) * 64 + w * 16 + kg;
            short8 b1 = *(const short8*)(t1 + off);
            short8 b2 = *(const short8*)(t2 + off);
            acc[fj] = __builtin_amdgcn_mfma_f32_16x16x32_bf16(ifrag, b1, acc[fj], 0, 0, 0);
            acc[fj] = __builtin_amdgcn_mfma_f32_16x16x32_bf16(ifrag, b2, acc[fj], 0, 0, 0);
        }
    }

    const int qrel0 = w * 16 + cr;
    #pragma unroll
    for (int fj = 0; fj < 20; ++fj) {
        int t = fj * 16 + cc;
        int j = j0 + t;
        #pragma unroll
        for (int e = 0; e < 4; ++e) {
            int qr = qrel0 + e;
            bool valid = (j >= 0) && (j < L_SEQ) && (t >= qr) && (t <= qr + 256);
            acc[fj][e] = valid ? acc[fj][e] : -3.0e38f;
        }
    }

    float mx[4], sm[4];
    #pragma unroll
    for (int e = 0; e < 4; ++e) {
        float m = acc[0][e];
        #pragma unroll
        for (int fj = 1; fj < 20; ++fj) m = fmaxf(m, acc[fj][e]);
        mx[e] = m;
    }
    #pragma unroll
    for (int msk = 1; msk < 16; msk <<= 1)
        #pragma unroll
        for (int e = 0; e < 4; ++e) mx[e] = fmaxf(mx[e], __shfl_xor(mx[e], msk));
    #pragma unroll
    for (int e = 0; e < 4; ++e) sm[e] = 0.f;
    #pragma unroll
    for (int fj = 0; fj < 20; ++fj)
        #pragma unroll
        for (int e = 0; e < 4; ++e) {
            float p = __expf(acc[fj][e] - mx[e]);
            acc[fj][e] = p;
            sm[e] += p;
        }
    #pragma unroll
    for (int msk = 1; msk < 16; msk <<= 1)
        #pragma unroll
        for (int e = 0; e < 4; ++e) sm[e] += __shfl_xor(sm[e], msk);
    float rinv[4];
    #pragma unroll
    for (int e = 0; e < 4; ++e) rinv[e] = 1.0f / sm[e];

    #pragma unroll
    for (int p = 0; p < 10; ++p) {
        int c = tid + p * 256;
        int t = c >> 3, d8 = (c & 7) << 3;
        #pragma unroll
        for (int e = 0; e < 8; ++e) {
            int d = d8 + e;
            int byte = (d * 640 + t * 2) ^ ((d & 7) << 4);
            *(short*)(KVb + byte) = vreg[p][e];
        }
    }

    f32x4 acc2[4];
    #pragma unroll
    for (int f = 0; f < 4; ++f) acc2[f] = (f32x4){0.f, 0.f, 0.f, 0.f};
    #pragma unroll
    for (int ch = 0; ch < 5; ++ch) {
        #pragma unroll
        for (int fjl = 0; fjl < 4; ++fjl) {
            int fj = ch * 4 + fjl;
            int col = fjl * 16 + cc;
            #pragma unroll
            for (int e = 0; e < 4; ++e)
                Ps[w * 16 + cr + e][col] = f2bs(acc[fj][e]);
        }
        if (ch == 0) __syncthreads();
        #pragma unroll
        for (int ks2 = 0; ks2 < 2; ++ks2) {
            short8 pa = *(const short8*)&Ps[w * 16 + fr][ks2 * 32 + kg];
            #pragma unroll
            for (int f = 0; f < 4; ++f) {
                int d = f * 16 + fr;
                int tg = ch * 64 + ks2 * 32 + kg;
                int byte = (d * 640 + tg * 2) ^ ((d & 7) << 4);
                short8 bv = *(const short8*)(KVb + byte);
                acc2[f] = __builtin_amdgcn_mfma_f32_16x16x32_bf16(pa, bv, acc2[f], 0, 0, 0);
            }
        }
    }

    #pragma unroll
    for (int f = 0; f < 4; ++f)
        #pragma unroll
        for (int e = 0; e < 4; ++e) {
            int row = qi0 + w * 16 + cr + e;
            int d = f * 16 + cc;
            ctxb[(size_t)row * HID_ + h * HD + d] = __float2bfloat16(acc2[f][e] * rinv[e]);
        }
}

// ---------------- launch ----------------
extern "C" void kernel_launch(void* const* d_in, const int* in_sizes, int n_in,
                              void* d_out, int out_size, void* d_ws, size_t ws_size,
                              hipStream_t stream) {
    const float* hid  = (const float*)d_in[0];
    const float* wq   = (const float*)d_in[2];
    const float* wk   = (const float*)d_in[3];
    const float* wv   = (const float*)d_in[4];
    const float* pk   = (const float*)d_in[5];
    const float* pq   = (const float*)d_in[6];
    const float* wo   = (const float*)d_in[7];
    const float* bo   = (const float*)d_in[8];
    const float* ln1g = (const float*)d_in[9];
    const float* ln1b = (const float*)d_in[10];
    const float* ln2g = (const float*)d_in[11];
    const float* ln2b = (const float*)d_in[12];
    const float* w1   = (const float*)d_in[13];
    const float* b1   = (const float*)d_in[14];
    const float* w2   = (const float*)d_in[15];
    const float* b2   = (const float*)d_in[16];
    float* out = (float*)d_out;

    char* ws = (char*)d_ws;
    size_t off = 0;
    auto alloc = [&](size_t bytes) -> void* {
        void* p = ws + off;
        off += (bytes + 255) & ~(size_t)255;
        return p;
    };
    const size_t BT_BYTES = (size_t)NH * NTILE * BT_TILE * 2 + 256;
    bf16* wqkvb = (bf16*)alloc((size_t)QKVS * HID_ * 2);
    bf16* wob   = (bf16*)alloc((size_t)HID_ * HID_ * 2);
    bf16* w1b   = (bf16*)alloc((size_t)HID_ * FF_ * 2);
    bf16* w2b   = (bf16*)alloc((size_t)HID_ * FF_ * 2);
    bf16* pkt   = (bf16*)alloc((size_t)NH * NPOS * HD * 2);
    bf16* pqt   = (bf16*)alloc((size_t)NH * NPOS * HD * 2);
    bf16* x1b   = (bf16*)alloc((size_t)L_SEQ * HID_ * 2);
    bf16* qkv   = (bf16*)alloc((size_t)L_SEQ * QKVS * 2);
    bf16* bt1   = (bf16*)alloc(BT_BYTES);
    bf16* bt2   = (bf16*)alloc(BT_BYTES);
    bf16* ctxb  = (bf16*)alloc((size_t)L_SEQ * HID_ * 2);
    float* hbuf = (float*)alloc((size_t)L_SEQ * HID_ * 4);
    bf16* x2b   = (bf16*)alloc((size_t)L_SEQ * HID_ * 2);
    bf16* ffb   = (bf16*)alloc((size_t)L_SEQ * FF_ * 2);
    (void)ws_size; (void)in_sizes; (void)n_in; (void)out_size;

    float* wopart  = (float*)ffb;   // dead before FF1 writes ffb
    float* ff2part = (float*)qkv;   // spans qkv+bt1, both dead after attn

    // weight + pos conversions (merged)
    k_wt_all<<<3072, 256, 0, stream>>>(wq, wk, wv, wo, w1, w2, wqkvb, wob, w1b, w2b);
    k_pos2<<<2056, 256, 0, stream>>>(pk, pq, pkt, pqt);

    // LN1
    k_layernorm<<<L_SEQ, 256, 0, stream>>>(hid, ln1g, ln1b, x1b);

    const int MN = L_SEQ * HID_;
    // fused QKV projection
    k_gemm64<0><<<dim3(32, 24, 1), 256, 0, stream>>>(x1b, wqkvb, qkv, nullptr, nullptr, QKVS, HID_, 32, MN);

    // band-aligned bias tables
    dim3 g_rp(NTILE, NH);
    k_relpos_bt<0><<<g_rp, 256, 0, stream>>>(qkv, pkt, bt1);
    k_relpos_bt<1><<<g_rp, 256, 0, stream>>>(qkv + 1024, pqt, bt2);

    // banded attention
    k_attn_mfma<<<dim3(NTILE, NH), 256, 0, stream>>>(qkv, qkv + 1024, qkv + 2048, bt1, bt2, ctxb);

    // Wo (split-K=2) + fused reduce(bias+residual)+LN2 -> hbuf, x2b
    k_gemm64<3><<<dim3(32, 8, 2), 256, 0, stream>>>(ctxb, wob, nullptr, wopart, nullptr, HID_, HID_, 16, MN);
    k_reduce_ln<2><<<L_SEQ, 256, 0, stream>>>(wopart, bo, hid, ln2g, ln2b, hbuf, x2b);

    // FF1: gelu(x2 @ w1 + b1) -> ffb
    k_gemm64<2><<<dim3(32, 32, 1), 256, 0, stream>>>(x2b, w1b, ffb, nullptr, b1, FF_, HID_, 32, MN);

    // FF2 (split-K=4) + reduce(bias+residual) -> out
    k_gemm64<3><<<dim3(32, 8, 4), 256, 0, stream>>>(ffb, w2b, nullptr, ff2part, nullptr, HID_, FF_, 32, MN);
    k_reduce<4><<<2048, 256, 0, stream>>>(ff2part, b2, hbuf, out);
}

// Round 9
// 289.724 us; speedup vs baseline: 3.5960x; 1.0752x over previous
//
#include <hip/hip_runtime.h>
#include <hip/hip_bf16.h>
#include <cstdint>

typedef __hip_bfloat16 bf16;
typedef __attribute__((ext_vector_type(8))) short short8;
typedef __attribute__((ext_vector_type(4))) float f32x4;
typedef __attribute__((address_space(1))) const unsigned int gu32;
typedef __attribute__((address_space(3))) unsigned int lu32;

#define L_SEQ 2048
#define HID_  1024
#define NH    16
#define HD    64
#define FF_   4096
#define NPOS  257   // 2W+1
#define WHALF 128
#define QKVS  3072  // fused qkv row stride
#define NTILE 32    // L_SEQ/64
#define BT_TILE (320 * 64)   // shorts per (h,tile) bias tile

__device__ inline short f2bs(float f) {
    bf16 b = __float2bfloat16(f);
    return *reinterpret_cast<short*>(&b);
}

// ---------------- merged prologue: 6 weight transposes + pos transposes + LN1 ----------------
// blocks [0,3072): weights; [3072,3329): pos tables; [3329,5377): LN1 rows
__global__ __launch_bounds__(256) void k_prep(const float* __restrict__ wq,
                                              const float* __restrict__ wk,
                                              const float* __restrict__ wv,
                                              const float* __restrict__ wo,
                                              const float* __restrict__ w1,
                                              const float* __restrict__ w2,
                                              const float* __restrict__ pk,
                                              const float* __restrict__ pq,
                                              const float* __restrict__ hid,
                                              const float* __restrict__ ln1g,
                                              const float* __restrict__ ln1b,
                                              bf16* __restrict__ wqkvb,
                                              bf16* __restrict__ wob,
                                              bf16* __restrict__ w1b,
                                              bf16* __restrict__ w2b,
                                              bf16* __restrict__ pkt,
                                              bf16* __restrict__ pqt,
                                              bf16* __restrict__ x1b) {
    __shared__ float smem[64 * 65];
    const int id = blockIdx.x, tid = threadIdx.x;

    if (id < 3072) {
        const float* src; bf16* dst; int K, N, tile;
        if (id < 768)       { int s = id >> 8; tile = id & 255;
                              src = s == 0 ? wq : (s == 1 ? wk : wv);
                              dst = wqkvb + (size_t)s * 1024 * 1024; K = 1024; N = 1024; }
        else if (id < 1024) { tile = id - 768;  src = wo; dst = wob; K = 1024; N = 1024; }
        else if (id < 2048) { tile = id - 1024; src = w1; dst = w1b; K = 1024; N = 4096; }
        else                { tile = id - 2048; src = w2; dst = w2b; K = 4096; N = 1024; }
        const int ktiles = K >> 6;
        const int k0 = (tile % ktiles) * 64, n0 = (tile / ktiles) * 64;
        float (*t)[65] = (float(*)[65])smem;
        const int c = tid & 63, r4 = tid >> 6;
        #pragma unroll
        for (int i = 0; i < 16; ++i)
            t[i * 4 + r4][c] = src[(size_t)(k0 + i * 4 + r4) * N + n0 + c];
        __syncthreads();
        #pragma unroll
        for (int i = 0; i < 16; ++i) {
            int n = i * 4 + r4;
            dst[(size_t)(n0 + n) * K + k0 + c] = __float2bfloat16(t[c][n]);
        }
    } else if (id < 3329) {
        const int T = NH * NPOS * HD;
        #pragma unroll
        for (int e = 0; e < 8; ++e) {
            int gi = (id - 3072) * 2048 + tid * 8 + e;
            if (gi < 2 * T) {
                const float* src = gi < T ? pk : pq;
                bf16* dst = gi < T ? pkt : pqt;
                int idx = gi < T ? gi : gi - T;
                int d = idx & 63;
                int r = idx >> 6;
                int tt = r % NPOS;
                int h = r / NPOS;
                dst[idx] = __float2bfloat16(src[((size_t)h * HD + d) * NPOS + tt]);
            }
        }
    } else {
        const int row = id - 3329;
        const int lane = tid & 63, w = tid >> 6;
        const float4 v = *(const float4*)(hid + (size_t)row * HID_ + tid * 4);
        float vals[4] = {v.x, v.y, v.z, v.w};
        float s = vals[0] + vals[1] + vals[2] + vals[3];
        float ss = vals[0]*vals[0] + vals[1]*vals[1] + vals[2]*vals[2] + vals[3]*vals[3];
        for (int off = 32; off; off >>= 1) { s += __shfl_down(s, off); ss += __shfl_down(ss, off); }
        float* rs = smem; float* rss = smem + 8; float* mv = smem + 16;
        if (lane == 0) { rs[w] = s; rss[w] = ss; }
        __syncthreads();
        if (tid == 0) {
            float S = rs[0] + rs[1] + rs[2] + rs[3];
            float SS = rss[0] + rss[1] + rss[2] + rss[3];
            float mean = S * (1.0f / HID_);
            float var = SS * (1.0f / HID_) - mean * mean;
            mv[0] = mean; mv[1] = rsqrtf(var + 1e-8f);
        }
        __syncthreads();
        const float mean = mv[0], rstd = mv[1];
        #pragma unroll
        for (int e = 0; e < 4; ++e) {
            int c = tid * 4 + e;
            x1b[(size_t)row * HID_ + c] = __float2bfloat16((vals[e] - mean) * rstd * ln1g[c] + ln1b[c]);
        }
    }
}

// ---------------- bf16 MFMA GEMM, 64x128 tile, BK=64, global_load_lds + 2-phase dbuf --------
// C[M,N] = A[M,K] * B[N,K]^T over K-range [z*kTiles*64, ...)
// EPI 0: outB = bf16(v);  EPI 2: outB = bf16(gelu(v+bias[col]));  EPI 3: outF[z*MN+o] = v
template <int EPI>
__global__ __launch_bounds__(256) void k_gemm64(const bf16* __restrict__ A,
                                                const bf16* __restrict__ B,
                                                bf16* __restrict__ outB,
                                                float* __restrict__ outF,
                                                const float* __restrict__ bias,
                                                int N, int K, int kTiles, int MN) {
    __shared__ __align__(16) short As[2][4096];   // [64][64] swizzled
    __shared__ __align__(16) short Bs[2][8192];   // [128][64] swizzled
    const int tid = threadIdx.x;
    const int bm = blockIdx.x * 64, bn = blockIdx.y * 128;
    const int lane = tid & 63, w = tid >> 6;
    const int wr = w >> 1, wc = w & 1;            // wave tile: 32 x 64
    const int k0base = blockIdx.z * kTiles * 64;

    // staging: one gload covers 8 full rows of 128B. Pre-swizzled global col slot.
    const int srow = lane >> 3;                   // 0..7 == row&7 (base rows 8-aligned)
    const int scol = ((lane & 7) ^ srow) * 8;     // swizzled k element offset (shorts)
    const short* Ag = (const short*)A;
    const short* Bg = (const short*)B;
    const size_t a_off0 = (size_t)(bm + w * 16 + srow) * K + scol;
    const size_t a_off1 = (size_t)(bm + w * 16 + 8 + srow) * K + scol;
    size_t b_off[4];
    #pragma unroll
    for (int gi = 0; gi < 4; ++gi)
        b_off[gi] = (size_t)(bn + w * 32 + gi * 8 + srow) * K + scol;

    auto stage = [&](int buf, int k0) {
        __builtin_amdgcn_global_load_lds((gu32*)(Ag + a_off0 + k0), (lu32*)&As[buf][(w * 16) * 64], 16, 0, 0);
        __builtin_amdgcn_global_load_lds((gu32*)(Ag + a_off1 + k0), (lu32*)&As[buf][(w * 16 + 8) * 64], 16, 0, 0);
        #pragma unroll
        for (int gi = 0; gi < 4; ++gi)
            __builtin_amdgcn_global_load_lds((gu32*)(Bg + b_off[gi] + k0), (lu32*)&Bs[buf][(w * 32 + gi * 8) * 64], 16, 0, 0);
    };

    // fragment read: byte = r*128 + ((ksub*64 + kq*16) ^ ((r&7)<<4))
    const int fr = lane & 15, kq = lane >> 4;

    f32x4 acc[2][4] = {};
    stage(0, k0base);
    __syncthreads();

    for (int t = 0; t < kTiles; ++t) {
        if (t + 1 < kTiles) stage((t + 1) & 1, k0base + (t + 1) * 64);
        const char* Ab = (const char*)As[t & 1];
        const char* Bb = (const char*)Bs[t & 1];
        #pragma unroll
        for (int ksub = 0; ksub < 2; ++ksub) {
            const int xb = ksub * 64 + kq * 16;
            short8 af[2], bfv[4];
            #pragma unroll
            for (int m2 = 0; m2 < 2; ++m2) {
                int r = wr * 32 + m2 * 16 + fr;
                af[m2] = *(const short8*)(Ab + (r << 7) + (xb ^ ((r & 7) << 4)));
            }
            #pragma unroll
            for (int n2 = 0; n2 < 4; ++n2) {
                int r = wc * 64 + n2 * 16 + fr;
                bfv[n2] = *(const short8*)(Bb + (r << 7) + (xb ^ ((r & 7) << 4)));
            }
            #pragma unroll
            for (int m2 = 0; m2 < 2; ++m2)
                #pragma unroll
                for (int n2 = 0; n2 < 4; ++n2)
                    acc[m2][n2] = __builtin_amdgcn_mfma_f32_16x16x32_bf16(af[m2], bfv[n2], acc[m2][n2], 0, 0, 0);
        }
        __syncthreads();
    }

    const int cr = kq * 4, cc = fr;
    #pragma unroll
    for (int m2 = 0; m2 < 2; ++m2) {
        #pragma unroll
        for (int n2 = 0; n2 < 4; ++n2) {
            const int col = bn + wc * 64 + n2 * 16 + cc;
            #pragma unroll
            for (int e = 0; e < 4; ++e) {
                const int row = bm + wr * 32 + m2 * 16 + cr + e;
                const size_t o = (size_t)row * N + col;
                float v = acc[m2][n2][e];
                if (EPI == 0) {
                    outB[o] = __float2bfloat16(v);
                } else if (EPI == 2) {
                    float xg = v + bias[col];
                    float gl = 0.5f * xg * (1.0f + erff(xg * 0.70710678f));
                    outB[o] = __float2bfloat16(gl);
                } else {
                    outF[(size_t)blockIdx.z * MN + o] = v;
                }
            }
        }
    }
}

// ---------------- split-K reduce + bias + residual + LayerNorm (row per block) ----------------
template <int S>
__global__ __launch_bounds__(256) void k_reduce_ln(const float* __restrict__ parts,
                                                   const float* __restrict__ bias,
                                                   const float* __restrict__ res,
                                                   const float* __restrict__ g,
                                                   const float* __restrict__ b,
                                                   float* __restrict__ outH,
                                                   bf16* __restrict__ outX) {
    const int row = blockIdx.x, tid = threadIdx.x;
    const int lane = tid & 63, w = tid >> 6;
    const int idx = row * 256 + tid;
    const float4* p = (const float4*)parts;
    float4 s = p[idx];
    #pragma unroll
    for (int ss = 1; ss < S; ++ss) {
        float4 t2 = p[idx + (size_t)ss * 524288];
        s.x += t2.x; s.y += t2.y; s.z += t2.z; s.w += t2.w;
    }
    float4 bb = ((const float4*)bias)[tid];
    float4 rr = ((const float4*)res)[idx];
    float vals[4] = {s.x + bb.x + rr.x, s.y + bb.y + rr.y, s.z + bb.z + rr.z, s.w + bb.w + rr.w};
    ((float4*)outH)[idx] = (float4){vals[0], vals[1], vals[2], vals[3]};

    float sum = vals[0] + vals[1] + vals[2] + vals[3];
    float ssq = vals[0]*vals[0] + vals[1]*vals[1] + vals[2]*vals[2] + vals[3]*vals[3];
    for (int off = 32; off; off >>= 1) { sum += __shfl_down(sum, off); ssq += __shfl_down(ssq, off); }
    __shared__ float rs[4], rss[4], mv[2];
    if (lane == 0) { rs[w] = sum; rss[w] = ssq; }
    __syncthreads();
    if (tid == 0) {
        float S2 = rs[0] + rs[1] + rs[2] + rs[3];
        float SS = rss[0] + rss[1] + rss[2] + rss[3];
        float mean = S2 * (1.0f / HID_);
        float var = SS * (1.0f / HID_) - mean * mean;
        mv[0] = mean; mv[1] = rsqrtf(var + 1e-8f);
    }
    __syncthreads();
    const float mean = mv[0], rstd = mv[1];
    #pragma unroll
    for (int e = 0; e < 4; ++e) {
        int c = tid * 4 + e;
        outX[(size_t)row * HID_ + c] = __float2bfloat16((vals[e] - mean) * rstd * g[c] + b[c]);
    }
}

// ---------------- split-K reduce + bias + residual (elementwise, fp32 out) ----------------
template <int S>
__global__ __launch_bounds__(256) void k_reduce(const float* __restrict__ parts,
                                                const float* __restrict__ bias,
                                                const float* __restrict__ res,
                                                float* __restrict__ out) {
    const int idx = blockIdx.x * 256 + threadIdx.x;
    const float4* p = (const float4*)parts;
    float4 s = p[idx];
    #pragma unroll
    for (int ss = 1; ss < S; ++ss) {
        float4 t2 = p[idx + (size_t)ss * 524288];
        s.x += t2.x; s.y += t2.y; s.z += t2.z; s.w += t2.w;
    }
    float4 bb = ((const float4*)bias)[idx & 255];
    float4 rr = ((const float4*)res)[idx];
    float4 o = {s.x + bb.x + rr.x, s.y + bb.y + rr.y, s.z + bb.z + rr.z, s.w + bb.w + rr.w};
    ((float4*)out)[idx] = o;
}

// ---------------- relpos -> band-aligned transposed bias tables (both modes, z selects) ------
// z=0 (c2p from Q): c2p[i][p] -> BT1[h][bq][t=p+il][il]  (coalesced via LDS re-tile)
// z=1 (p2c from K): p2c[j][u] -> BT2[h][bq][t=j-64bq+128][il=(j+u-128)&63]
__global__ __launch_bounds__(256) void k_relpos2(const bf16* __restrict__ qkv,
                                                 const bf16* __restrict__ pkt,
                                                 const bf16* __restrict__ pqt,
                                                 bf16* __restrict__ bt1,
                                                 bf16* __restrict__ bt2) {
    const int bq = blockIdx.x, h = blockIdx.y, mode = blockIdx.z;
    const int r0 = bq * 64;
    const int tid = threadIdx.x, lane = tid & 63, w = tid >> 6;
    const int fr = lane & 15, kg = (lane >> 4) << 3;
    const int cr = (lane >> 4) << 2, cc = lane & 15;
    const bf16* X = mode == 0 ? qkv : qkv + 1024;
    const bf16* Pt = mode == 0 ? pkt : pqt;
    bf16* bt = mode == 0 ? bt1 : bt2;

    short8 af[2];
    #pragma unroll
    for (int ks = 0; ks < 2; ++ks)
        af[ks] = *(const short8*)&X[(size_t)(r0 + w * 16 + fr) * QKVS + h * HD + ks * 32 + kg];

    f32x4 acc[20];
    #pragma unroll
    for (int fj = 0; fj < 20; ++fj) acc[fj] = (f32x4){0.f, 0.f, 0.f, 0.f};

    #pragma unroll
    for (int fj = 0; fj < 20; ++fj) {
        int p = fj * 16 + fr;
        int pc = p < NPOS ? p : (NPOS - 1);
        #pragma unroll
        for (int ks = 0; ks < 2; ++ks) {
            short8 bp = *(const short8*)&Pt[((size_t)h * NPOS + pc) * HD + ks * 32 + kg];
            acc[fj] = __builtin_amdgcn_mfma_f32_16x16x32_bf16(af[ks], bp, acc[fj], 0, 0, 0);
        }
    }

    if (mode == 0) {
        __shared__ short ld[64][328];
        #pragma unroll
        for (int fj = 0; fj < 20; ++fj) {
            int p = fj * 16 + cc;
            if (p < NPOS) {
                #pragma unroll
                for (int e = 0; e < 4; ++e)
                    ld[w * 16 + cr + e][p] = f2bs(acc[fj][e]);
            }
        }
        __syncthreads();
        short* outp = (short*)bt + (size_t)(h * NTILE + bq) * BT_TILE;
        #pragma unroll
        for (int i = 0; i < 10; ++i) {
            int idx8 = (tid + i * 256) * 8;
            int t = idx8 >> 6, il0 = idx8 & 63;
            short8 v;
            #pragma unroll
            for (int e = 0; e < 8; ++e) {
                int il = il0 + e, p = t - il;
                v[e] = (p >= 0 && p < NPOS) ? ld[il][p] : (short)0;
            }
            *(short8*)(outp + t * 64 + il0) = v;
        }
    } else {
        #pragma unroll
        for (int fj = 0; fj < 20; ++fj) {
            int p = fj * 16 + cc;
            if (p < NPOS) {
                #pragma unroll
                for (int e = 0; e < 4; ++e) {
                    int rloc = w * 16 + cr + e;
                    int j = r0 + rloc;
                    int s = j + p - 128;
                    if (s >= 0 && s < L_SEQ) {
                        int tb = s >> 6, il = s & 63;
                        int t = j - tb * 64 + 128;
                        bt[((size_t)(h * NTILE + tb) * 320 + t) * 64 + il] =
                            __float2bfloat16(acc[fj][e]);
                    }
                }
            }
        }
    }
}

// ---------------- MFMA banded attention (bias via identity-MFMA) ----------------
__global__ __launch_bounds__(256, 3) void k_attn_mfma(const bf16* __restrict__ qb,
                                                      const bf16* __restrict__ kb,
                                                      const bf16* __restrict__ vb,
                                                      const bf16* __restrict__ bt1,
                                                      const bf16* __restrict__ bt2,
                                                      bf16* __restrict__ ctxb) {
    const int bq = blockIdx.x, h = blockIdx.y;
    const int qi0 = bq * 64, j0 = qi0 - WHALF;
    const int tid = threadIdx.x, lane = tid & 63, w = tid >> 6;
    const int fr = lane & 15, kq = lane >> 4, kg = kq << 3;
    const int cr = kq << 2, cc = fr;

    __shared__ short KVs[20480];            // K: [320][64] swizzled; then Vt: [64][320] swizzled
    __shared__ __align__(16) short Ps[64][72];
    char* KVb = (char*)KVs;

    #pragma unroll
    for (int p = 0; p < 10; ++p) {
        int c = tid + p * 256;
        int t = c >> 3, d8 = (c & 7) << 3;
        int j = j0 + t;
        short8 v = {};
        if (j >= 0 && j < L_SEQ) v = *(const short8*)&kb[(size_t)j * QKVS + h * HD + d8];
        int byte = (t * 128 + d8 * 2) ^ ((t & 7) << 4);
        *(short8*)(KVb + byte) = v;
    }
    short8 aq[2];
    #pragma unroll
    for (int ks = 0; ks < 2; ++ks)
        aq[ks] = *(const short8*)&qb[(size_t)(qi0 + w * 16 + fr) * QKVS + h * HD + ks * 32 + kg];

    short8 ifrag = {};
    {
        int d = fr - kg;
        if (d >= 0 && d < 8) ifrag[d] = (short)0x3F80;
    }
    __syncthreads();

    f32x4 acc[20];
    #pragma unroll
    for (int fj = 0; fj < 20; ++fj) acc[fj] = (f32x4){0.f, 0.f, 0.f, 0.f};
    #pragma unroll
    for (int ks = 0; ks < 2; ++ks) {
        #pragma unroll
        for (int fj = 0; fj < 20; ++fj) {
            int t = fj * 16 + fr;
            int byte = (t * 128 + (ks * 32 + kg) * 2) ^ ((t & 7) << 4);
            short8 bk = *(const short8*)(KVb + byte);
            acc[fj] = __builtin_amdgcn_mfma_f32_16x16x32_bf16(aq[ks], bk, acc[fj], 0, 0, 0);
        }
    }
    __syncthreads();

    short8 vreg[10];
    #pragma unroll
    for (int p = 0; p < 10; ++p) {
        int c = tid + p * 256;
        int t = c >> 3, d8 = (c & 7) << 3;
        int j = j0 + t;
        short8 v = {};
        if (j >= 0 && j < L_SEQ) v = *(const short8*)&vb[(size_t)j * QKVS + h * HD + d8];
        vreg[p] = v;
    }

    {
        const short* t1 = (const short*)bt1 + (size_t)(h * NTILE + bq) * BT_TILE;
        const short* t2 = (const short*)bt2 + (size_t)(h * NTILE + bq) * BT_TILE;
        #pragma unroll
        for (int fj = 0; fj < 20; ++fj) {
            int off = (fj * 16 + fr) * 64 + w * 16 + kg;
            short8 b1 = *(const short8*)(t1 + off);
            short8 b2 = *(const short8*)(t2 + off);
            acc[fj] = __builtin_amdgcn_mfma_f32_16x16x32_bf16(ifrag, b1, acc[fj], 0, 0, 0);
            acc[fj] = __builtin_amdgcn_mfma_f32_16x16x32_bf16(ifrag, b2, acc[fj], 0, 0, 0);
        }
    }

    const int qrel0 = w * 16 + cr;
    #pragma unroll
    for (int fj = 0; fj < 20; ++fj) {
        int t = fj * 16 + cc;
        int j = j0 + t;
        #pragma unroll
        for (int e = 0; e < 4; ++e) {
            int qr = qrel0 + e;
            bool valid = (j >= 0) && (j < L_SEQ) && (t >= qr) && (t <= qr + 256);
            acc[fj][e] = valid ? acc[fj][e] : -3.0e38f;
        }
    }

    float mx[4], sm[4];
    #pragma unroll
    for (int e = 0; e < 4; ++e) {
        float m = acc[0][e];
        #pragma unroll
        for (int fj = 1; fj < 20; ++fj) m = fmaxf(m, acc[fj][e]);
        mx[e] = m;
    }
    #pragma unroll
    for (int msk = 1; msk < 16; msk <<= 1)
        #pragma unroll
        for (int e = 0; e < 4; ++e) mx[e] = fmaxf(mx[e], __shfl_xor(mx[e], msk));
    #pragma unroll
    for (int e = 0; e < 4; ++e) sm[e] = 0.f;
    #pragma unroll
    for (int fj = 0; fj < 20; ++fj)
        #pragma unroll
        for (int e = 0; e < 4; ++e) {
            float p = __expf(acc[fj][e] - mx[e]);
            acc[fj][e] = p;
            sm[e] += p;
        }
    #pragma unroll
    for (int msk = 1; msk < 16; msk <<= 1)
        #pragma unroll
        for (int e = 0; e < 4; ++e) sm[e] += __shfl_xor(sm[e], msk);
    float rinv[4];
    #pragma unroll
    for (int e = 0; e < 4; ++e) rinv[e] = 1.0f / sm[e];

    #pragma unroll
    for (int p = 0; p < 10; ++p) {
        int c = tid + p * 256;
        int t = c >> 3, d8 = (c & 7) << 3;
        #pragma unroll
        for (int e = 0; e < 8; ++e) {
            int d = d8 + e;
            int byte = (d * 640 + t * 2) ^ ((d & 7) << 4);
            *(short*)(KVb + byte) = vreg[p][e];
        }
    }

    f32x4 acc2[4];
    #pragma unroll
    for (int f = 0; f < 4; ++f) acc2[f] = (f32x4){0.f, 0.f, 0.f, 0.f};
    #pragma unroll
    for (int ch = 0; ch < 5; ++ch) {
        #pragma unroll
        for (int fjl = 0; fjl < 4; ++fjl) {
            int fj = ch * 4 + fjl;
            int col = fjl * 16 + cc;
            #pragma unroll
            for (int e = 0; e < 4; ++e)
                Ps[w * 16 + cr + e][col] = f2bs(acc[fj][e]);
        }
        if (ch == 0) __syncthreads();
        #pragma unroll
        for (int ks2 = 0; ks2 < 2; ++ks2) {
            short8 pa = *(const short8*)&Ps[w * 16 + fr][ks2 * 32 + kg];
            #pragma unroll
            for (int f = 0; f < 4; ++f) {
                int d = f * 16 + fr;
                int tg = ch * 64 + ks2 * 32 + kg;
                int byte = (d * 640 + tg * 2) ^ ((d & 7) << 4);
                short8 bv = *(const short8*)(KVb + byte);
                acc2[f] = __builtin_amdgcn_mfma_f32_16x16x32_bf16(pa, bv, acc2[f], 0, 0, 0);
            }
        }
    }

    #pragma unroll
    for (int f = 0; f < 4; ++f)
        #pragma unroll
        for (int e = 0; e < 4; ++e) {
            int row = qi0 + w * 16 + cr + e;
            int d = f * 16 + cc;
            ctxb[(size_t)row * HID_ + h * HD + d] = __float2bfloat16(acc2[f][e] * rinv[e]);
        }
}

// ---------------- launch ----------------
extern "C" void kernel_launch(void* const* d_in, const int* in_sizes, int n_in,
                              void* d_out, int out_size, void* d_ws, size_t ws_size,
                              hipStream_t stream) {
    const float* hid  = (const float*)d_in[0];
    const float* wq   = (const float*)d_in[2];
    const float* wk   = (const float*)d_in[3];
    const float* wv   = (const float*)d_in[4];
    const float* pk   = (const float*)d_in[5];
    const float* pq   = (const float*)d_in[6];
    const float* wo   = (const float*)d_in[7];
    const float* bo   = (const float*)d_in[8];
    const float* ln1g = (const float*)d_in[9];
    const float* ln1b = (const float*)d_in[10];
    const float* ln2g = (const float*)d_in[11];
    const float* ln2b = (const float*)d_in[12];
    const float* w1   = (const float*)d_in[13];
    const float* b1   = (const float*)d_in[14];
    const float* w2   = (const float*)d_in[15];
    const float* b2   = (const float*)d_in[16];
    float* out = (float*)d_out;

    char* ws = (char*)d_ws;
    size_t off = 0;
    auto alloc = [&](size_t bytes) -> void* {
        void* p = ws + off;
        off += (bytes + 255) & ~(size_t)255;
        return p;
    };
    const size_t BT_BYTES = (size_t)NH * NTILE * BT_TILE * 2 + 256;
    bf16* wqkvb = (bf16*)alloc((size_t)QKVS * HID_ * 2);
    bf16* wob   = (bf16*)alloc((size_t)HID_ * HID_ * 2);
    bf16* w1b   = (bf16*)alloc((size_t)HID_ * FF_ * 2);
    bf16* w2b   = (bf16*)alloc((size_t)HID_ * FF_ * 2);
    bf16* pkt   = (bf16*)alloc((size_t)NH * NPOS * HD * 2);
    bf16* pqt   = (bf16*)alloc((size_t)NH * NPOS * HD * 2);
    bf16* x1b   = (bf16*)alloc((size_t)L_SEQ * HID_ * 2);
    bf16* qkv   = (bf16*)alloc((size_t)L_SEQ * QKVS * 2);
    bf16* bt1   = (bf16*)alloc(BT_BYTES);
    bf16* bt2   = (bf16*)alloc(BT_BYTES);
    bf16* ctxb  = (bf16*)alloc((size_t)L_SEQ * HID_ * 2);
    float* hbuf = (float*)alloc((size_t)L_SEQ * HID_ * 4);
    bf16* x2b   = (bf16*)alloc((size_t)L_SEQ * HID_ * 2);
    bf16* ffb   = (bf16*)alloc((size_t)L_SEQ * FF_ * 2);
    (void)ws_size; (void)in_sizes; (void)n_in; (void)out_size;

    float* wopart  = (float*)ffb;   // dead before FF1 writes ffb
    float* ff2part = (float*)qkv;   // 16 MB spans qkv(+bt1 head), both dead after attn

    // merged prologue: weights + pos tables + LN1
    k_prep<<<5377, 256, 0, stream>>>(wq, wk, wv, wo, w1, w2, pk, pq, hid, ln1g, ln1b,
                                     wqkvb, wob, w1b, w2b, pkt, pqt, x1b);

    const int MN = L_SEQ * HID_;
    // fused QKV projection (BK=64)
    k_gemm64<0><<<dim3(32, 24, 1), 256, 0, stream>>>(x1b, wqkvb, qkv, nullptr, nullptr, QKVS, HID_, 16, MN);

    // band-aligned bias tables (both modes in one launch)
    k_relpos2<<<dim3(NTILE, NH, 2), 256, 0, stream>>>(qkv, pkt, pqt, bt1, bt2);

    // banded attention
    k_attn_mfma<<<dim3(NTILE, NH), 256, 0, stream>>>(qkv, qkv + 1024, qkv + 2048, bt1, bt2, ctxb);

    // Wo (split-K=2) + fused reduce(bias+residual)+LN2 -> hbuf, x2b
    k_gemm64<3><<<dim3(32, 8, 2), 256, 0, stream>>>(ctxb, wob, nullptr, wopart, nullptr, HID_, HID_, 8, MN);
    k_reduce_ln<2><<<L_SEQ, 256, 0, stream>>>(wopart, bo, hid, ln2g, ln2b, hbuf, x2b);

    // FF1: gelu(x2 @ w1 + b1) -> ffb
    k_gemm64<2><<<dim3(32, 32, 1), 256, 0, stream>>>(x2b, w1b, ffb, nullptr, b1, FF_, HID_, 16, MN);

    // FF2 (split-K=2) + reduce(bias+residual) -> out
    k_gemm64<3><<<dim3(32, 8, 2), 256, 0, stream>>>(ffb, w2b, nullptr, ff2part, nullptr, HID_, FF_, 32, MN);
    k_reduce<2><<<2048, 256, 0, stream>>>(ff2part, b2, hbuf, out);
}